// Round 1
// baseline (2549.314 us; speedup 1.0000x reference)
//
#include <hip/hip_runtime.h>

#define NNODES 100000
#define NEDGES 1600000
#define NGRAPHS 64
#define HID 128
#define OUTD 256
#define NLAYERS 5
#define BN_EPS 1e-5f

// ---------------- CSR build ----------------
__global__ void k_hist(const int* __restrict__ dstv, int* __restrict__ deg) {
    int e = blockIdx.x * 256 + threadIdx.x;
    if (e < NEDGES) atomicAdd(&deg[dstv[e]], 1);
}

__global__ void k_scan(const int* __restrict__ deg, int* __restrict__ off) {
    __shared__ int lds[1024];
    const int CH = 98;  // 1024*98 = 100352 >= NNODES
    int t = threadIdx.x;
    int base = t * CH;
    int s = 0;
    for (int i = 0; i < CH; i++) {
        int idx = base + i;
        if (idx < NNODES) s += deg[idx];
    }
    lds[t] = s;
    __syncthreads();
    for (int o = 1; o < 1024; o <<= 1) {
        int v = (t >= o) ? lds[t - o] : 0;
        __syncthreads();
        lds[t] += v;
        __syncthreads();
    }
    int run = lds[t] - s;  // exclusive prefix
    for (int i = 0; i < CH; i++) {
        int idx = base + i;
        if (idx < NNODES) { off[idx] = run; run += deg[idx]; }
    }
    if (t == 1023) off[NNODES] = lds[1023];
}

__global__ void k_fill(const int* __restrict__ srcv, const int* __restrict__ dstv,
                       const int* __restrict__ off, int* __restrict__ cur,
                       int* __restrict__ adj) {
    int e = blockIdx.x * 256 + threadIdx.x;
    if (e < NEDGES) {
        int d = dstv[e];
        int p = atomicAdd(&cur[d], 1);
        adj[off[d] + p] = srcv[e];
    }
}

// ---------------- per-layer kernels ----------------
// out[node] = h[node] + sum_{nbr} h[nbr]   (fused z = h + agg)
__global__ void k_agg(const float* __restrict__ h, const int* __restrict__ off,
                      const int* __restrict__ adj, float* __restrict__ out) {
    int tid = threadIdx.x;
    int node = blockIdx.x * 8 + (tid >> 5);  // 32 threads per node, grid*8 == NNODES
    int d4 = tid & 31;                       // float4 lane: covers 128 dims
    const float4* h4 = (const float4*)h;
    float4 v = h4[(size_t)node * 32 + d4];
    int e0 = off[node], e1 = off[node + 1];
    for (int e = e0; e < e1; e++) {
        int s = adj[e];
        float4 u = h4[(size_t)s * 32 + d4];
        v.x += u.x; v.y += u.y; v.z += u.z; v.w += u.w;
    }
    ((float4*)out)[(size_t)node * 32 + d4] = v;
}

// C = A' @ W + bias ; mode 0: A'=A ; mode 1: A' = relu(A*scale[k]+shift[k])
__global__ __launch_bounds__(256) void k_gemm(
    const float* __restrict__ A, const float* __restrict__ W,
    const float* __restrict__ bias, float* __restrict__ C,
    int mode, const float* __restrict__ scale, const float* __restrict__ shift) {
    __shared__ float As[64 * 33];    // [row][k] padded, broadcast-read
    __shared__ float Ws[32 * 128];   // [k][n]
    int tid = threadIdx.x;
    int tx = tid & 15;       // 8 output cols each
    int ty = tid >> 4;       // 4 output rows each
    int row0 = blockIdx.x * 64;

    float acc[4][8];
#pragma unroll
    for (int i = 0; i < 4; i++)
#pragma unroll
        for (int j = 0; j < 8; j++) acc[i][j] = 0.f;

    for (int kb = 0; kb < 4; kb++) {
        // stage A tile: 64 rows x 32 k
#pragma unroll
        for (int p = 0; p < 2; p++) {
            int f = tid + p * 256;
            int r = f >> 3, kq = f & 7;
            int row = row0 + r;
            if (row >= NNODES) row = NNODES - 1;  // clamp; stores are guarded
            float4 v = *(const float4*)&A[(size_t)row * 128 + kb * 32 + kq * 4];
            if (mode) {
                int k = kb * 32 + kq * 4;
                float4 sc = *(const float4*)&scale[k];
                float4 sh = *(const float4*)&shift[k];
                v.x = fmaxf(v.x * sc.x + sh.x, 0.f);
                v.y = fmaxf(v.y * sc.y + sh.y, 0.f);
                v.z = fmaxf(v.z * sc.z + sh.z, 0.f);
                v.w = fmaxf(v.w * sc.w + sh.w, 0.f);
            }
            As[r * 33 + kq * 4 + 0] = v.x;
            As[r * 33 + kq * 4 + 1] = v.y;
            As[r * 33 + kq * 4 + 2] = v.z;
            As[r * 33 + kq * 4 + 3] = v.w;
        }
        // stage W tile: 32 k x 128 n
#pragma unroll
        for (int p = 0; p < 4; p++) {
            int f = tid + p * 256;
            int k = f >> 5, n4 = f & 31;
            *(float4*)&Ws[k * 128 + n4 * 4] =
                *(const float4*)&W[(size_t)(kb * 32 + k) * 128 + n4 * 4];
        }
        __syncthreads();
#pragma unroll 4
        for (int k = 0; k < 32; k++) {
            float av[4];
#pragma unroll
            for (int i = 0; i < 4; i++) av[i] = As[(ty * 4 + i) * 33 + k];
            float4 w0 = *(float4*)&Ws[k * 128 + tx * 8];
            float4 w1 = *(float4*)&Ws[k * 128 + tx * 8 + 4];
            float wv[8] = {w0.x, w0.y, w0.z, w0.w, w1.x, w1.y, w1.z, w1.w};
#pragma unroll
            for (int i = 0; i < 4; i++)
#pragma unroll
                for (int j = 0; j < 8; j++) acc[i][j] += av[i] * wv[j];
        }
        __syncthreads();
    }
    float4 bb0 = *(const float4*)&bias[tx * 8];
    float4 bb1 = *(const float4*)&bias[tx * 8 + 4];
#pragma unroll
    for (int i = 0; i < 4; i++) {
        int row = row0 + ty * 4 + i;
        if (row < NNODES) {
            float4 o0 = make_float4(acc[i][0] + bb0.x, acc[i][1] + bb0.y,
                                    acc[i][2] + bb0.z, acc[i][3] + bb0.w);
            float4 o1 = make_float4(acc[i][4] + bb1.x, acc[i][5] + bb1.y,
                                    acc[i][6] + bb1.z, acc[i][7] + bb1.w);
            *(float4*)&C[(size_t)row * 128 + tx * 8] = o0;
            *(float4*)&C[(size_t)row * 128 + tx * 8 + 4] = o1;
        }
    }
}

// column sums + sumsq -> stats[0..127]=sum, stats[128..255]=sumsq
__global__ void k_reduce(const float* __restrict__ X, float* __restrict__ stats) {
    int d = threadIdx.x;  // 128
    float s = 0.f, q = 0.f;
    for (int r = blockIdx.x; r < NNODES; r += gridDim.x) {
        float v = X[(size_t)r * 128 + d];
        s += v; q += v * v;
    }
    atomicAdd(&stats[d], s);
    atomicAdd(&stats[128 + d], q);
}

__global__ void k_finalize(const float* __restrict__ stats, const float* __restrict__ gamma,
                           const float* __restrict__ beta, float* __restrict__ scale,
                           float* __restrict__ shift) {
    int d = threadIdx.x;  // 128
    float m = stats[d] * (1.f / NNODES);
    float v = stats[128 + d] * (1.f / NNODES) - m * m;
    float sc = gamma[d] * rsqrtf(v + BN_EPS);
    scale[d] = sc;
    shift[d] = beta[d] - m * sc;
}

// h += relu(t2*scale[c] + shift[c])
__global__ void k_resid(float* __restrict__ h, const float* __restrict__ t2,
                        const float* __restrict__ scale, const float* __restrict__ shift) {
    int i = blockIdx.x * 256 + threadIdx.x;  // float4 index
    int c4 = (i & 31) * 4;
    float4 sc = *(const float4*)&scale[c4];
    float4 sh = *(const float4*)&shift[c4];
    float4 t = ((const float4*)t2)[i];
    float4 hv = ((float4*)h)[i];
    hv.x += fmaxf(t.x * sc.x + sh.x, 0.f);
    hv.y += fmaxf(t.y * sc.y + sh.y, 0.f);
    hv.z += fmaxf(t.z * sc.z + sh.z, 0.f);
    hv.w += fmaxf(t.w * sc.w + sh.w, 0.f);
    ((float4*)h)[i] = hv;
}

// ---------------- pooling + projection ----------------
__global__ void k_counts(const int* __restrict__ batch, float* __restrict__ cnt) {
    int g = threadIdx.x;
    if (g >= NGRAPHS) return;
    auto lb = [&](int key) {
        int lo = 0, hi = NNODES;
        while (lo < hi) {
            int mid = (lo + hi) >> 1;
            if (batch[mid] < key) lo = mid + 1; else hi = mid;
        }
        return lo;
    };
    cnt[g] = (float)(lb(g + 1) - lb(g));
}

__global__ void k_pool(const float* __restrict__ h, const int* __restrict__ batch,
                       float* __restrict__ pooled) {
    int d = threadIdx.x;  // 128
    int n0 = blockIdx.x * 512;
    if (n0 >= NNODES) return;
    int n1 = n0 + 512;
    if (n1 > NNODES) n1 = NNODES;
    int gcur = batch[n0];
    float acc = 0.f;
    for (int n = n0; n < n1; n++) {
        int g = batch[n];
        if (g != gcur) {
            atomicAdd(&pooled[gcur * 128 + d], acc);
            acc = 0.f;
            gcur = g;
        }
        acc += h[(size_t)n * 128 + d];
    }
    atomicAdd(&pooled[gcur * 128 + d], acc);
}

__global__ void k_proj(const float* __restrict__ pooled, const float* __restrict__ cnt,
                       const float* __restrict__ wp, const float* __restrict__ bp,
                       float* __restrict__ out) {
    __shared__ float prow[128];
    int g = blockIdx.x, c = threadIdx.x;  // 256 threads
    if (c < 128) prow[c] = pooled[g * 128 + c] / fmaxf(cnt[g], 1.f);
    __syncthreads();
    float acc = bp[c];
    for (int k = 0; k < 128; k++) acc += prow[k] * wp[k * 256 + c];
    out[g * 256 + c] = acc;
}

extern "C" void kernel_launch(void* const* d_in, const int* in_sizes, int n_in,
                              void* d_out, int out_size, void* d_ws, size_t ws_size,
                              hipStream_t stream) {
    const float* x    = (const float*)d_in[0];
    const int*   eidx = (const int*)d_in[1];
    const int*   batch= (const int*)d_in[2];
    const float* w1   = (const float*)d_in[3];
    const float* b1   = (const float*)d_in[4];
    const float* g1   = (const float*)d_in[5];
    const float* be1  = (const float*)d_in[6];
    const float* w2   = (const float*)d_in[7];
    const float* b2   = (const float*)d_in[8];
    const float* gbn  = (const float*)d_in[9];
    const float* bbn  = (const float*)d_in[10];
    const float* wp   = (const float*)d_in[11];
    const float* bp   = (const float*)d_in[12];

    float* out  = (float*)d_out;
    float* gemb = out;                          // [64,256]
    float* h    = out + (size_t)NGRAPHS * OUTD; // node_emb lives in d_out

    char* w = (char*)d_ws;
    float* bufA  = (float*)w; w += (size_t)NNODES * 128 * 4;  // agg / t2
    float* bufB  = (float*)w; w += (size_t)NNODES * 128 * 4;  // y
    int*   off   = (int*)w;   w += (size_t)(NNODES + 8) * 4;
    int*   cur   = (int*)w;   w += (size_t)NNODES * 4;        // deg, then cursor
    int*   adj   = (int*)w;   w += (size_t)NEDGES * 4;
    float* stats = (float*)w; w += 512 * 4;                   // [sum1|sq1|sum2|sq2]
    float* scale1= (float*)w; w += 128 * 4;
    float* shift1= (float*)w; w += 128 * 4;
    float* scale2= (float*)w; w += 128 * 4;
    float* shift2= (float*)w; w += 128 * 4;
    float* pooled= (float*)w; w += (size_t)NGRAPHS * HID * 4;
    float* gcnt  = (float*)w; w += NGRAPHS * 4;

    const int* srcv = eidx;
    const int* dstv = eidx + NEDGES;

    // h = x
    hipMemcpyAsync(h, x, (size_t)NNODES * 128 * 4, hipMemcpyDeviceToDevice, stream);

    // CSR build (per-launch; ws is poisoned each call)
    hipMemsetAsync(cur, 0, (size_t)NNODES * 4, stream);
    k_hist<<<NEDGES / 256, 256, 0, stream>>>(dstv, cur);
    k_scan<<<1, 1024, 0, stream>>>(cur, off);
    hipMemsetAsync(cur, 0, (size_t)NNODES * 4, stream);
    k_fill<<<NEDGES / 256, 256, 0, stream>>>(srcv, dstv, off, cur, adj);

    for (int i = 0; i < NLAYERS; i++) {
        hipMemsetAsync(stats, 0, 512 * 4, stream);
        k_agg<<<NNODES / 8, 256, 0, stream>>>(h, off, adj, bufA);
        k_gemm<<<(NNODES + 63) / 64, 256, 0, stream>>>(
            bufA, w1 + (size_t)i * HID * HID, b1 + i * HID, bufB, 0, nullptr, nullptr);
        k_reduce<<<512, 128, 0, stream>>>(bufB, stats);
        k_finalize<<<1, 128, 0, stream>>>(stats, g1 + i * HID, be1 + i * HID, scale1, shift1);
        k_gemm<<<(NNODES + 63) / 64, 256, 0, stream>>>(
            bufB, w2 + (size_t)i * HID * HID, b2 + i * HID, bufA, 1, scale1, shift1);
        k_reduce<<<512, 128, 0, stream>>>(bufA, stats + 256);
        k_finalize<<<1, 128, 0, stream>>>(stats + 256, gbn + i * HID, bbn + i * HID, scale2, shift2);
        k_resid<<<NNODES * 128 / 4 / 256, 256, 0, stream>>>(h, bufA, scale2, shift2);
    }

    // pooling + projection
    hipMemsetAsync(pooled, 0, (size_t)(NGRAPHS * HID + NGRAPHS) * 4, stream);
    k_counts<<<1, 64, 0, stream>>>(batch, gcnt);
    k_pool<<<(NNODES + 511) / 512, 128, 0, stream>>>(h, batch, pooled);
    k_proj<<<NGRAPHS, 256, 0, stream>>>(pooled, gcnt, wp, bp, gemb);
}

// Round 2
// 1815.124 us; speedup vs baseline: 1.4045x; 1.4045x over previous
//
#include <hip/hip_runtime.h>

#define NNODES 100000
#define NEDGES 1600000
#define NGRAPHS 64
#define HID 128
#define OUTD 256
#define NLAYERS 5
#define BN_EPS 1e-5f

typedef __attribute__((ext_vector_type(8))) short short8;
typedef __attribute__((ext_vector_type(4))) float f32x4;

__device__ inline unsigned short f2b(float f) {
    union { float f; unsigned int u; } a; a.f = f;
    unsigned int u = a.u;
    return (unsigned short)((u + 0x7FFF + ((u >> 16) & 1)) >> 16);  // RNE
}

// ---------------- CSR build ----------------
__global__ void k_hist(const int* __restrict__ dstv, int* __restrict__ deg) {
    int e = blockIdx.x * 256 + threadIdx.x;
    if (e < NEDGES) atomicAdd(&deg[dstv[e]], 1);
}

// 3-kernel coalesced scan: partial sums -> block-offset scan -> local scans
__global__ void k_scan1(const int* __restrict__ deg, int* __restrict__ bsum) {
    __shared__ int lds[512];
    int t = threadIdx.x, idx = blockIdx.x * 512 + t;
    lds[t] = (idx < NNODES) ? deg[idx] : 0;
    __syncthreads();
    for (int o = 256; o > 0; o >>= 1) {
        if (t < o) lds[t] += lds[t + o];
        __syncthreads();
    }
    if (t == 0) bsum[blockIdx.x] = lds[0];
}

__global__ void k_scan2(const int* __restrict__ bsum, int* __restrict__ boff,
                        int* __restrict__ off) {
    __shared__ int lds[256];
    int t = threadIdx.x;
    int v = (t < 196) ? bsum[t] : 0;
    lds[t] = v;
    __syncthreads();
    for (int o = 1; o < 256; o <<= 1) {
        int u = (t >= o) ? lds[t - o] : 0;
        __syncthreads();
        lds[t] += u;
        __syncthreads();
    }
    if (t < 196) boff[t] = lds[t] - v;  // exclusive
    if (t == 0) off[NNODES] = NEDGES;
}

__global__ void k_scan3(const int* __restrict__ deg, const int* __restrict__ boff,
                        int* __restrict__ off) {
    __shared__ int lds[512];
    int t = threadIdx.x, idx = blockIdx.x * 512 + t;
    int v = (idx < NNODES) ? deg[idx] : 0;
    lds[t] = v;
    __syncthreads();
    for (int o = 1; o < 512; o <<= 1) {
        int u = (t >= o) ? lds[t - o] : 0;
        __syncthreads();
        lds[t] += u;
        __syncthreads();
    }
    if (idx < NNODES) off[idx] = boff[blockIdx.x] + (lds[t] - v);
}

__global__ void k_fill(const int* __restrict__ srcv, const int* __restrict__ dstv,
                       const int* __restrict__ off, int* __restrict__ cur,
                       int* __restrict__ adj) {
    int e = blockIdx.x * 256 + threadIdx.x;
    if (e < NEDGES) {
        int d = dstv[e];
        int p = atomicAdd(&cur[d], 1);
        adj[off[d] + p] = srcv[e];
    }
}

// ---------------- W transpose to bf16 (all 10 matrices, once) ----------------
__global__ void k_wt(const float* __restrict__ w1, const float* __restrict__ w2,
                     unsigned short* __restrict__ WT) {
    int t = blockIdx.x * 256 + threadIdx.x;  // 0 .. 163839
    int mat = t >> 14;
    int rem = t & 16383;
    int k = rem >> 7, n = rem & 127;
    const float* src = (mat < 5) ? &w1[(size_t)mat * 16384] : &w2[(size_t)(mat - 5) * 16384];
    WT[(size_t)mat * 16384 + n * 128 + k] = f2b(src[k * 128 + n]);
}

// ---------------- aggregation: out = h + sum_nbr h ----------------
__global__ void k_agg(const float* __restrict__ h, const int* __restrict__ off,
                      const int* __restrict__ adj, float* __restrict__ out) {
    int tid = threadIdx.x;
    int node = blockIdx.x * 8 + (tid >> 5);
    int d4 = tid & 31;
    const float4* h4 = (const float4*)h;
    float4 v = h4[(size_t)node * 32 + d4];
    int e0 = off[node], e1 = off[node + 1];
    for (int e = e0; e < e1; e++) {
        int s = adj[e];
        float4 u = h4[(size_t)s * 32 + d4];
        v.x += u.x; v.y += u.y; v.z += u.z; v.w += u.w;
    }
    ((float4*)out)[(size_t)node * 32 + d4] = v;
}

// ---------------- MFMA GEMM: C = A' @ W + bias, fused column stats ----------
// mode 0: A'=A ; mode 1: A' = relu(A*scale[k]+shift[k])
// Per block: 128 rows x 128 cols. Per wave: 32 rows (2 x 16-row tiles).
// B-frags come straight from L2-resident bf16 W^T[n][k]; A-frags from global.
__global__ __launch_bounds__(256) void k_gemm_mfma(
    const float* __restrict__ A, const unsigned short* __restrict__ WT,
    const float* __restrict__ bias, float* __restrict__ C,
    int mode, const float* __restrict__ scale, const float* __restrict__ shift,
    float* __restrict__ stats) {
    __shared__ float lstat[256];  // col sums [0:128], col sumsq [128:256]
    int tid = threadIdx.x;
    int wave = tid >> 6;
    int lane = tid & 63;
    int q = lane >> 4;    // quad
    int l16 = lane & 15;
    int rowbase = blockIdx.x * 128 + wave * 32;

    f32x4 acc[2][8];
#pragma unroll
    for (int rt = 0; rt < 2; rt++)
#pragma unroll
        for (int nt = 0; nt < 8; nt++) acc[rt][nt] = (f32x4){0.f, 0.f, 0.f, 0.f};

    for (int kc = 0; kc < 4; kc++) {
        int k0 = kc * 32 + q * 8;  // this lane's 8 k values
        short8 bf[8];
#pragma unroll
        for (int nt = 0; nt < 8; nt++)
            bf[nt] = *(const short8*)&WT[(size_t)(nt * 16 + l16) * 128 + k0];

        float4 s0, s1, t0, t1;
        if (mode) {
            s0 = *(const float4*)&scale[k0]; s1 = *(const float4*)&scale[k0 + 4];
            t0 = *(const float4*)&shift[k0]; t1 = *(const float4*)&shift[k0 + 4];
        }
#pragma unroll
        for (int rt = 0; rt < 2; rt++) {
            int row = rowbase + rt * 16 + l16;
            if (row >= NNODES) row = NNODES - 1;  // clamped; store/stats guarded
            const float* ap = &A[(size_t)row * 128 + k0];
            float4 a0 = *(const float4*)ap;
            float4 a1 = *(const float4*)(ap + 4);
            if (mode) {
                a0.x = fmaxf(a0.x * s0.x + t0.x, 0.f);
                a0.y = fmaxf(a0.y * s0.y + t0.y, 0.f);
                a0.z = fmaxf(a0.z * s0.z + t0.z, 0.f);
                a0.w = fmaxf(a0.w * s0.w + t0.w, 0.f);
                a1.x = fmaxf(a1.x * s1.x + t1.x, 0.f);
                a1.y = fmaxf(a1.y * s1.y + t1.y, 0.f);
                a1.z = fmaxf(a1.z * s1.z + t1.z, 0.f);
                a1.w = fmaxf(a1.w * s1.w + t1.w, 0.f);
            }
            union { short8 s; unsigned short u[8]; } cvt;
            cvt.u[0] = f2b(a0.x); cvt.u[1] = f2b(a0.y);
            cvt.u[2] = f2b(a0.z); cvt.u[3] = f2b(a0.w);
            cvt.u[4] = f2b(a1.x); cvt.u[5] = f2b(a1.y);
            cvt.u[6] = f2b(a1.z); cvt.u[7] = f2b(a1.w);
#pragma unroll
            for (int nt = 0; nt < 8; nt++)
                acc[rt][nt] = __builtin_amdgcn_mfma_f32_16x16x32_bf16(
                    cvt.s, bf[nt], acc[rt][nt], 0, 0, 0);
        }
    }

    // epilogue: bias add + store + fused column sum/sumsq
    lstat[tid] = 0.f;
    __syncthreads();
#pragma unroll
    for (int nt = 0; nt < 8; nt++) {
        float b = bias[nt * 16 + l16];
        float csum = 0.f, csq = 0.f;
#pragma unroll
        for (int rt = 0; rt < 2; rt++) {
            int rb = rowbase + rt * 16 + q * 4;
#pragma unroll
            for (int r = 0; r < 4; r++) {
                int row = rb + r;
                if (row < NNODES) {
                    float v = acc[rt][nt][r] + b;
                    C[(size_t)row * 128 + nt * 16 + l16] = v;
                    csum += v; csq += v * v;
                }
            }
        }
        csum += __shfl_xor(csum, 16, 64); csq += __shfl_xor(csq, 16, 64);
        csum += __shfl_xor(csum, 32, 64); csq += __shfl_xor(csq, 32, 64);
        if (q == 0) {
            atomicAdd(&lstat[nt * 16 + l16], csum);
            atomicAdd(&lstat[128 + nt * 16 + l16], csq);
        }
    }
    __syncthreads();
    atomicAdd(&stats[tid], lstat[tid]);
}

__global__ void k_finalize(const float* __restrict__ stats, const float* __restrict__ gamma,
                           const float* __restrict__ beta, float* __restrict__ scale,
                           float* __restrict__ shift) {
    int d = threadIdx.x;
    float m = stats[d] * (1.f / NNODES);
    float v = stats[128 + d] * (1.f / NNODES) - m * m;
    float sc = gamma[d] * rsqrtf(v + BN_EPS);
    scale[d] = sc;
    shift[d] = beta[d] - m * sc;
}

// h += relu(t2*scale[c] + shift[c])
__global__ void k_resid(float* __restrict__ h, const float* __restrict__ t2,
                        const float* __restrict__ scale, const float* __restrict__ shift) {
    int i = blockIdx.x * 256 + threadIdx.x;
    int c4 = (i & 31) * 4;
    float4 sc = *(const float4*)&scale[c4];
    float4 sh = *(const float4*)&shift[c4];
    float4 t = ((const float4*)t2)[i];
    float4 hv = ((float4*)h)[i];
    hv.x += fmaxf(t.x * sc.x + sh.x, 0.f);
    hv.y += fmaxf(t.y * sc.y + sh.y, 0.f);
    hv.z += fmaxf(t.z * sc.z + sh.z, 0.f);
    hv.w += fmaxf(t.w * sc.w + sh.w, 0.f);
    ((float4*)h)[i] = hv;
}

// ---------------- pooling + projection ----------------
__global__ void k_counts(const int* __restrict__ batch, float* __restrict__ cnt) {
    int g = threadIdx.x;
    if (g >= NGRAPHS) return;
    auto lb = [&](int key) {
        int lo = 0, hi = NNODES;
        while (lo < hi) {
            int mid = (lo + hi) >> 1;
            if (batch[mid] < key) lo = mid + 1; else hi = mid;
        }
        return lo;
    };
    cnt[g] = (float)(lb(g + 1) - lb(g));
}

__global__ void k_pool(const float* __restrict__ h, const int* __restrict__ batch,
                       float* __restrict__ pooled) {
    int d = threadIdx.x;
    int n0 = blockIdx.x * 512;
    if (n0 >= NNODES) return;
    int n1 = n0 + 512;
    if (n1 > NNODES) n1 = NNODES;
    int gcur = batch[n0];
    float acc = 0.f;
    for (int n = n0; n < n1; n++) {
        int g = batch[n];
        if (g != gcur) {
            atomicAdd(&pooled[gcur * 128 + d], acc);
            acc = 0.f;
            gcur = g;
        }
        acc += h[(size_t)n * 128 + d];
    }
    atomicAdd(&pooled[gcur * 128 + d], acc);
}

__global__ void k_proj(const float* __restrict__ pooled, const float* __restrict__ cnt,
                       const float* __restrict__ wp, const float* __restrict__ bp,
                       float* __restrict__ out) {
    __shared__ float prow[128];
    int g = blockIdx.x, c = threadIdx.x;
    if (c < 128) prow[c] = pooled[g * 128 + c] / fmaxf(cnt[g], 1.f);
    __syncthreads();
    float acc = bp[c];
    for (int k = 0; k < 128; k++) acc += prow[k] * wp[k * 256 + c];
    out[g * 256 + c] = acc;
}

extern "C" void kernel_launch(void* const* d_in, const int* in_sizes, int n_in,
                              void* d_out, int out_size, void* d_ws, size_t ws_size,
                              hipStream_t stream) {
    const float* x    = (const float*)d_in[0];
    const int*   eidx = (const int*)d_in[1];
    const int*   batch= (const int*)d_in[2];
    const float* w1   = (const float*)d_in[3];
    const float* b1   = (const float*)d_in[4];
    const float* g1   = (const float*)d_in[5];
    const float* be1  = (const float*)d_in[6];
    const float* w2   = (const float*)d_in[7];
    const float* b2   = (const float*)d_in[8];
    const float* gbn  = (const float*)d_in[9];
    const float* bbn  = (const float*)d_in[10];
    const float* wp   = (const float*)d_in[11];
    const float* bp   = (const float*)d_in[12];

    float* out  = (float*)d_out;
    float* gemb = out;                          // [64,256]
    float* h    = out + (size_t)NGRAPHS * OUTD; // node_emb lives in d_out

    char* w = (char*)d_ws;
    float* bufA  = (float*)w; w += (size_t)NNODES * 128 * 4;  // agg / t2
    float* bufB  = (float*)w; w += (size_t)NNODES * 128 * 4;  // y
    int*   off   = (int*)w;   w += (size_t)(NNODES + 8) * 4;
    int*   cur   = (int*)w;   w += (size_t)NNODES * 4;        // deg, then cursor
    int*   adj   = (int*)w;   w += (size_t)NEDGES * 4;
    unsigned short* WT = (unsigned short*)w; w += (size_t)10 * 16384 * 2;
    int*   bsum  = (int*)w;   w += 256 * 4;
    int*   boff  = (int*)w;   w += 256 * 4;
    float* stats = (float*)w; w += 512 * 4;                   // [sum1|sq1|sum2|sq2]
    float* scale1= (float*)w; w += 128 * 4;
    float* shift1= (float*)w; w += 128 * 4;
    float* scale2= (float*)w; w += 128 * 4;
    float* shift2= (float*)w; w += 128 * 4;
    float* pooled= (float*)w; w += (size_t)NGRAPHS * HID * 4;
    float* gcnt  = (float*)w; w += NGRAPHS * 4;

    const int* srcv = eidx;
    const int* dstv = eidx + NEDGES;

    // h = x
    hipMemcpyAsync(h, x, (size_t)NNODES * 128 * 4, hipMemcpyDeviceToDevice, stream);

    // W transposes (bf16), once
    k_wt<<<640, 256, 0, stream>>>(w1, w2, WT);

    // CSR build
    hipMemsetAsync(cur, 0, (size_t)NNODES * 4, stream);
    k_hist<<<NEDGES / 256, 256, 0, stream>>>(dstv, cur);
    k_scan1<<<196, 512, 0, stream>>>(cur, bsum);
    k_scan2<<<1, 256, 0, stream>>>(bsum, boff, off);
    k_scan3<<<196, 512, 0, stream>>>(cur, boff, off);
    hipMemsetAsync(cur, 0, (size_t)NNODES * 4, stream);
    k_fill<<<NEDGES / 256, 256, 0, stream>>>(srcv, dstv, off, cur, adj);

    const int GB = (NNODES + 127) / 128;  // 782
    for (int i = 0; i < NLAYERS; i++) {
        hipMemsetAsync(stats, 0, 512 * 4, stream);
        k_agg<<<NNODES / 8, 256, 0, stream>>>(h, off, adj, bufA);
        k_gemm_mfma<<<GB, 256, 0, stream>>>(
            bufA, WT + (size_t)i * 16384, b1 + i * HID, bufB, 0, nullptr, nullptr, stats);
        k_finalize<<<1, 128, 0, stream>>>(stats, g1 + i * HID, be1 + i * HID, scale1, shift1);
        k_gemm_mfma<<<GB, 256, 0, stream>>>(
            bufB, WT + (size_t)(5 + i) * 16384, b2 + i * HID, bufA, 1, scale1, shift1, stats + 256);
        k_finalize<<<1, 128, 0, stream>>>(stats + 256, gbn + i * HID, bbn + i * HID, scale2, shift2);
        k_resid<<<NNODES * 128 / 4 / 256, 256, 0, stream>>>(h, bufA, scale2, shift2);
    }

    // pooling + projection
    hipMemsetAsync(pooled, 0, (size_t)(NGRAPHS * HID + NGRAPHS) * 4, stream);
    k_counts<<<1, 64, 0, stream>>>(batch, gcnt);
    k_pool<<<(NNODES + 511) / 512, 128, 0, stream>>>(h, batch, pooled);
    k_proj<<<NGRAPHS, 256, 0, stream>>>(pooled, gcnt, wp, bp, gemb);
}

// Round 3
// 1595.863 us; speedup vs baseline: 1.5975x; 1.1374x over previous
//
#include <hip/hip_runtime.h>

#define NNODES 100000
#define NEDGES 1600000
#define NGRAPHS 64
#define HID 128
#define OUTD 256
#define NLAYERS 5
#define BN_EPS 1e-5f

typedef __attribute__((ext_vector_type(8))) short short8;
typedef __attribute__((ext_vector_type(4))) float f32x4;

__device__ inline unsigned short f2b(float f) {
    union { float f; unsigned int u; } a; a.f = f;
    unsigned int u = a.u;
    return (unsigned short)((u + 0x7FFF + ((u >> 16) & 1)) >> 16);  // RNE
}
__device__ inline float b2f(unsigned short b) {
    union { unsigned int u; float f; } a; a.u = ((unsigned int)b) << 16;
    return a.f;
}

// ---------------- init: h = x (fp32) and hb = bf16(x) ----------------
__global__ void k_init(const float* __restrict__ x, float* __restrict__ h,
                       ushort* __restrict__ hb) {
    int i = blockIdx.x * 256 + threadIdx.x;  // float4 index
    float4 v = ((const float4*)x)[i];
    ((float4*)h)[i] = v;
    ushort4 o;
    o.x = f2b(v.x); o.y = f2b(v.y); o.z = f2b(v.z); o.w = f2b(v.w);
    ((ushort4*)hb)[i] = o;
}

// ---------------- CSR build ----------------
__global__ void k_hist(const int* __restrict__ dstv, int* __restrict__ deg) {
    int e = blockIdx.x * 256 + threadIdx.x;
    if (e < NEDGES) atomicAdd(&deg[dstv[e]], 1);
}

__global__ void k_scan1(const int* __restrict__ deg, int* __restrict__ bsum) {
    __shared__ int lds[512];
    int t = threadIdx.x, idx = blockIdx.x * 512 + t;
    lds[t] = (idx < NNODES) ? deg[idx] : 0;
    __syncthreads();
    for (int o = 256; o > 0; o >>= 1) {
        if (t < o) lds[t] += lds[t + o];
        __syncthreads();
    }
    if (t == 0) bsum[blockIdx.x] = lds[0];
}

__global__ void k_scan2(const int* __restrict__ bsum, int* __restrict__ boff,
                        int* __restrict__ off) {
    __shared__ int lds[256];
    int t = threadIdx.x;
    int v = (t < 196) ? bsum[t] : 0;
    lds[t] = v;
    __syncthreads();
    for (int o = 1; o < 256; o <<= 1) {
        int u = (t >= o) ? lds[t - o] : 0;
        __syncthreads();
        lds[t] += u;
        __syncthreads();
    }
    if (t < 196) boff[t] = lds[t] - v;  // exclusive
    if (t == 0) off[NNODES] = NEDGES;
}

__global__ void k_scan3(const int* __restrict__ deg, const int* __restrict__ boff,
                        int* __restrict__ off) {
    __shared__ int lds[512];
    int t = threadIdx.x, idx = blockIdx.x * 512 + t;
    int v = (idx < NNODES) ? deg[idx] : 0;
    lds[t] = v;
    __syncthreads();
    for (int o = 1; o < 512; o <<= 1) {
        int u = (t >= o) ? lds[t - o] : 0;
        __syncthreads();
        lds[t] += u;
        __syncthreads();
    }
    if (idx < NNODES) off[idx] = boff[blockIdx.x] + (lds[t] - v);
}

__global__ void k_fill(const int* __restrict__ srcv, const int* __restrict__ dstv,
                       const int* __restrict__ off, int* __restrict__ cur,
                       int* __restrict__ adj) {
    int e = blockIdx.x * 256 + threadIdx.x;
    if (e < NEDGES) {
        int d = dstv[e];
        int p = atomicAdd(&cur[d], 1);
        adj[off[d] + p] = srcv[e];
    }
}

// ---------------- W transpose to bf16 (all 10 matrices, once) ----------------
__global__ void k_wt(const float* __restrict__ w1, const float* __restrict__ w2,
                     unsigned short* __restrict__ WT) {
    int t = blockIdx.x * 256 + threadIdx.x;
    int mat = t >> 14;
    int rem = t & 16383;
    int k = rem >> 7, n = rem & 127;
    const float* src = (mat < 5) ? &w1[(size_t)mat * 16384] : &w2[(size_t)(mat - 5) * 16384];
    WT[(size_t)mat * 16384 + n * 128 + k] = f2b(src[k * 128 + n]);
}

// ---------------- aggregation: zb = bf16(h + sum_nbr hb) ----------------
__global__ void k_agg(const float* __restrict__ h, const ushort* __restrict__ hb,
                      const int* __restrict__ off, const int* __restrict__ adj,
                      ushort* __restrict__ zb) {
    int tid = threadIdx.x;
    int node = blockIdx.x * 8 + (tid >> 5);
    int d4 = tid & 31;
    float4 v = ((const float4*)h)[(size_t)node * 32 + d4];  // self in fp32
    const ushort4* hb4 = (const ushort4*)hb;
    int e0 = off[node], e1 = off[node + 1];
    for (int e = e0; e < e1; e++) {
        int s = adj[e];
        ushort4 u = hb4[(size_t)s * 32 + d4];
        v.x += b2f(u.x); v.y += b2f(u.y); v.z += b2f(u.z); v.w += b2f(u.w);
    }
    ushort4 o;
    o.x = f2b(v.x); o.y = f2b(v.y); o.z = f2b(v.z); o.w = f2b(v.w);
    ((ushort4*)zb)[(size_t)node * 32 + d4] = o;
}

// ---------------- GEMM1: C = zb @ W + bias (A already bf16), fused stats ----
__global__ __launch_bounds__(256) void k_gemm1(
    const ushort* __restrict__ A, const unsigned short* __restrict__ WT,
    const float* __restrict__ bias, float* __restrict__ C,
    float* __restrict__ stats) {
    __shared__ float lstat[256];
    int tid = threadIdx.x;
    int wave = tid >> 6;
    int lane = tid & 63;
    int q = lane >> 4;
    int l16 = lane & 15;
    int rowbase = blockIdx.x * 128 + wave * 32;

    f32x4 acc[2][8];
#pragma unroll
    for (int rt = 0; rt < 2; rt++)
#pragma unroll
        for (int nt = 0; nt < 8; nt++) acc[rt][nt] = (f32x4){0.f, 0.f, 0.f, 0.f};

    for (int kc = 0; kc < 4; kc++) {
        int k0 = kc * 32 + q * 8;
        short8 bf[8];
#pragma unroll
        for (int nt = 0; nt < 8; nt++)
            bf[nt] = *(const short8*)&WT[(size_t)(nt * 16 + l16) * 128 + k0];
#pragma unroll
        for (int rt = 0; rt < 2; rt++) {
            int row = rowbase + rt * 16 + l16;
            if (row >= NNODES) row = NNODES - 1;
            short8 av = *(const short8*)&A[(size_t)row * 128 + k0];
#pragma unroll
            for (int nt = 0; nt < 8; nt++)
                acc[rt][nt] = __builtin_amdgcn_mfma_f32_16x16x32_bf16(
                    av, bf[nt], acc[rt][nt], 0, 0, 0);
        }
    }

    lstat[tid] = 0.f;
    __syncthreads();
#pragma unroll
    for (int nt = 0; nt < 8; nt++) {
        float b = bias[nt * 16 + l16];
        float csum = 0.f, csq = 0.f;
#pragma unroll
        for (int rt = 0; rt < 2; rt++) {
            int rb = rowbase + rt * 16 + q * 4;
#pragma unroll
            for (int r = 0; r < 4; r++) {
                int row = rb + r;
                if (row < NNODES) {
                    float v = acc[rt][nt][r] + b;
                    C[(size_t)row * 128 + nt * 16 + l16] = v;
                    csum += v; csq += v * v;
                }
            }
        }
        csum += __shfl_xor(csum, 16, 64); csq += __shfl_xor(csq, 16, 64);
        csum += __shfl_xor(csum, 32, 64); csq += __shfl_xor(csq, 32, 64);
        if (q == 0) {
            atomicAdd(&lstat[nt * 16 + l16], csum);
            atomicAdd(&lstat[128 + nt * 16 + l16], csq);
        }
    }
    __syncthreads();
    atomicAdd(&stats[tid], lstat[tid]);
}

// ---------------- GEMM2: C = relu(A*scale+shift) @ W + bias, fused stats ----
__global__ __launch_bounds__(256) void k_gemm2(
    const float* __restrict__ A, const unsigned short* __restrict__ WT,
    const float* __restrict__ bias, float* __restrict__ C,
    const float* __restrict__ scale, const float* __restrict__ shift,
    float* __restrict__ stats) {
    __shared__ float lstat[256];
    int tid = threadIdx.x;
    int wave = tid >> 6;
    int lane = tid & 63;
    int q = lane >> 4;
    int l16 = lane & 15;
    int rowbase = blockIdx.x * 128 + wave * 32;

    f32x4 acc[2][8];
#pragma unroll
    for (int rt = 0; rt < 2; rt++)
#pragma unroll
        for (int nt = 0; nt < 8; nt++) acc[rt][nt] = (f32x4){0.f, 0.f, 0.f, 0.f};

    for (int kc = 0; kc < 4; kc++) {
        int k0 = kc * 32 + q * 8;
        short8 bf[8];
#pragma unroll
        for (int nt = 0; nt < 8; nt++)
            bf[nt] = *(const short8*)&WT[(size_t)(nt * 16 + l16) * 128 + k0];

        float4 s0 = *(const float4*)&scale[k0];
        float4 s1 = *(const float4*)&scale[k0 + 4];
        float4 t0 = *(const float4*)&shift[k0];
        float4 t1 = *(const float4*)&shift[k0 + 4];
#pragma unroll
        for (int rt = 0; rt < 2; rt++) {
            int row = rowbase + rt * 16 + l16;
            if (row >= NNODES) row = NNODES - 1;
            const float* ap = &A[(size_t)row * 128 + k0];
            float4 a0 = *(const float4*)ap;
            float4 a1 = *(const float4*)(ap + 4);
            a0.x = fmaxf(a0.x * s0.x + t0.x, 0.f);
            a0.y = fmaxf(a0.y * s0.y + t0.y, 0.f);
            a0.z = fmaxf(a0.z * s0.z + t0.z, 0.f);
            a0.w = fmaxf(a0.w * s0.w + t0.w, 0.f);
            a1.x = fmaxf(a1.x * s1.x + t1.x, 0.f);
            a1.y = fmaxf(a1.y * s1.y + t1.y, 0.f);
            a1.z = fmaxf(a1.z * s1.z + t1.z, 0.f);
            a1.w = fmaxf(a1.w * s1.w + t1.w, 0.f);
            union { short8 s; unsigned short u[8]; } cvt;
            cvt.u[0] = f2b(a0.x); cvt.u[1] = f2b(a0.y);
            cvt.u[2] = f2b(a0.z); cvt.u[3] = f2b(a0.w);
            cvt.u[4] = f2b(a1.x); cvt.u[5] = f2b(a1.y);
            cvt.u[6] = f2b(a1.z); cvt.u[7] = f2b(a1.w);
#pragma unroll
            for (int nt = 0; nt < 8; nt++)
                acc[rt][nt] = __builtin_amdgcn_mfma_f32_16x16x32_bf16(
                    cvt.s, bf[nt], acc[rt][nt], 0, 0, 0);
        }
    }

    lstat[tid] = 0.f;
    __syncthreads();
#pragma unroll
    for (int nt = 0; nt < 8; nt++) {
        float b = bias[nt * 16 + l16];
        float csum = 0.f, csq = 0.f;
#pragma unroll
        for (int rt = 0; rt < 2; rt++) {
            int rb = rowbase + rt * 16 + q * 4;
#pragma unroll
            for (int r = 0; r < 4; r++) {
                int row = rb + r;
                if (row < NNODES) {
                    float v = acc[rt][nt][r] + b;
                    C[(size_t)row * 128 + nt * 16 + l16] = v;
                    csum += v; csq += v * v;
                }
            }
        }
        csum += __shfl_xor(csum, 16, 64); csq += __shfl_xor(csq, 16, 64);
        csum += __shfl_xor(csum, 32, 64); csq += __shfl_xor(csq, 32, 64);
        if (q == 0) {
            atomicAdd(&lstat[nt * 16 + l16], csum);
            atomicAdd(&lstat[128 + nt * 16 + l16], csq);
        }
    }
    __syncthreads();
    atomicAdd(&stats[tid], lstat[tid]);
}

__global__ void k_finalize(const float* __restrict__ stats, const float* __restrict__ gamma,
                           const float* __restrict__ beta, float* __restrict__ scale,
                           float* __restrict__ shift) {
    int d = threadIdx.x;
    float m = stats[d] * (1.f / NNODES);
    float v = stats[128 + d] * (1.f / NNODES) - m * m;
    float sc = gamma[d] * rsqrtf(v + BN_EPS);
    scale[d] = sc;
    shift[d] = beta[d] - m * sc;
}

// h += relu(t2*scale+shift); hb = bf16(h)
__global__ void k_resid(float* __restrict__ h, ushort* __restrict__ hb,
                        const float* __restrict__ t2,
                        const float* __restrict__ scale, const float* __restrict__ shift) {
    int i = blockIdx.x * 256 + threadIdx.x;
    int c4 = (i & 31) * 4;
    float4 sc = *(const float4*)&scale[c4];
    float4 sh = *(const float4*)&shift[c4];
    float4 t = ((const float4*)t2)[i];
    float4 hv = ((float4*)h)[i];
    hv.x += fmaxf(t.x * sc.x + sh.x, 0.f);
    hv.y += fmaxf(t.y * sc.y + sh.y, 0.f);
    hv.z += fmaxf(t.z * sc.z + sh.z, 0.f);
    hv.w += fmaxf(t.w * sc.w + sh.w, 0.f);
    ((float4*)h)[i] = hv;
    ushort4 o;
    o.x = f2b(hv.x); o.y = f2b(hv.y); o.z = f2b(hv.z); o.w = f2b(hv.w);
    ((ushort4*)hb)[i] = o;
}

// ---------------- pooling + projection ----------------
__global__ void k_counts(const int* __restrict__ batch, float* __restrict__ cnt) {
    int g = threadIdx.x;
    if (g >= NGRAPHS) return;
    auto lb = [&](int key) {
        int lo = 0, hi = NNODES;
        while (lo < hi) {
            int mid = (lo + hi) >> 1;
            if (batch[mid] < key) lo = mid + 1; else hi = mid;
        }
        return lo;
    };
    cnt[g] = (float)(lb(g + 1) - lb(g));
}

// 782 blocks x 256 thr; block reduces 128 rows, per-graph-segment LDS tree
__global__ void k_pool(const float* __restrict__ h, const int* __restrict__ batch,
                       float* __restrict__ pooled) {
    __shared__ float4 red[256];
    int t = threadIdx.x;
    int d4 = t & 31, sub = t >> 5;
    int n0 = blockIdx.x * 128;
    if (n0 >= NNODES) return;
    int n1 = n0 + 128; if (n1 > NNODES) n1 = NNODES;
    int glo = batch[n0], ghi = batch[n1 - 1];
    for (int g = glo; g <= ghi; g++) {
        float4 acc = make_float4(0.f, 0.f, 0.f, 0.f);
        for (int r = n0 + sub; r < n1; r += 8) {
            if (batch[r] == g) {
                float4 v = ((const float4*)h)[(size_t)r * 32 + d4];
                acc.x += v.x; acc.y += v.y; acc.z += v.z; acc.w += v.w;
            }
        }
        red[t] = acc;
        __syncthreads();
        if (sub < 4) {
            float4 o = red[t + 128];
            red[t].x += o.x; red[t].y += o.y; red[t].z += o.z; red[t].w += o.w;
        }
        __syncthreads();
        if (sub < 2) {
            float4 o = red[t + 64];
            red[t].x += o.x; red[t].y += o.y; red[t].z += o.z; red[t].w += o.w;
        }
        __syncthreads();
        if (sub == 0) {
            float4 o = red[t + 32];
            float4 a = red[t];
            a.x += o.x; a.y += o.y; a.z += o.z; a.w += o.w;
            atomicAdd(&pooled[g * 128 + d4 * 4 + 0], a.x);
            atomicAdd(&pooled[g * 128 + d4 * 4 + 1], a.y);
            atomicAdd(&pooled[g * 128 + d4 * 4 + 2], a.z);
            atomicAdd(&pooled[g * 128 + d4 * 4 + 3], a.w);
        }
        __syncthreads();
    }
}

__global__ void k_proj(const float* __restrict__ pooled, const float* __restrict__ cnt,
                       const float* __restrict__ wp, const float* __restrict__ bp,
                       float* __restrict__ out) {
    __shared__ float prow[128];
    int g = blockIdx.x, c = threadIdx.x;
    if (c < 128) prow[c] = pooled[g * 128 + c] / fmaxf(cnt[g], 1.f);
    __syncthreads();
    float acc = bp[c];
    for (int k = 0; k < 128; k++) acc += prow[k] * wp[k * 256 + c];
    out[g * 256 + c] = acc;
}

extern "C" void kernel_launch(void* const* d_in, const int* in_sizes, int n_in,
                              void* d_out, int out_size, void* d_ws, size_t ws_size,
                              hipStream_t stream) {
    const float* x    = (const float*)d_in[0];
    const int*   eidx = (const int*)d_in[1];
    const int*   batch= (const int*)d_in[2];
    const float* w1   = (const float*)d_in[3];
    const float* b1   = (const float*)d_in[4];
    const float* g1   = (const float*)d_in[5];
    const float* be1  = (const float*)d_in[6];
    const float* w2   = (const float*)d_in[7];
    const float* b2   = (const float*)d_in[8];
    const float* gbn  = (const float*)d_in[9];
    const float* bbn  = (const float*)d_in[10];
    const float* wp   = (const float*)d_in[11];
    const float* bp   = (const float*)d_in[12];

    float* out  = (float*)d_out;
    float* gemb = out;                          // [64,256]
    float* h    = out + (size_t)NGRAPHS * OUTD; // node_emb lives in d_out

    char* w = (char*)d_ws;
    float* bufA  = (float*)w; w += (size_t)NNODES * 128 * 4;  // t2 (fp32); zb aliases
    float* bufB  = (float*)w; w += (size_t)NNODES * 128 * 4;  // t (fp32)
    ushort* hb   = (ushort*)w; w += (size_t)NNODES * 128 * 2; // bf16 mirror of h
    int*   off   = (int*)w;   w += (size_t)(NNODES + 8) * 4;
    int*   cur   = (int*)w;   w += (size_t)NNODES * 4;
    int*   adj   = (int*)w;   w += (size_t)NEDGES * 4;
    unsigned short* WT = (unsigned short*)w; w += (size_t)10 * 16384 * 2;
    int*   bsum  = (int*)w;   w += 256 * 4;
    int*   boff  = (int*)w;   w += 256 * 4;
    float* stats = (float*)w; w += 512 * 4;
    float* scale1= (float*)w; w += 128 * 4;
    float* shift1= (float*)w; w += 128 * 4;
    float* scale2= (float*)w; w += 128 * 4;
    float* shift2= (float*)w; w += 128 * 4;
    float* pooled= (float*)w; w += (size_t)NGRAPHS * HID * 4;
    float* gcnt  = (float*)w; w += NGRAPHS * 4;

    ushort* zb = (ushort*)bufA;  // bf16 z, dead before gemm2 overwrites bufA

    const int* srcv = eidx;
    const int* dstv = eidx + NEDGES;

    // h = x, hb = bf16(x)
    k_init<<<NNODES * 32 / 256, 256, 0, stream>>>(x, h, hb);

    // W transposes (bf16), once
    k_wt<<<640, 256, 0, stream>>>(w1, w2, WT);

    // CSR build
    hipMemsetAsync(cur, 0, (size_t)NNODES * 4, stream);
    k_hist<<<NEDGES / 256, 256, 0, stream>>>(dstv, cur);
    k_scan1<<<196, 512, 0, stream>>>(cur, bsum);
    k_scan2<<<1, 256, 0, stream>>>(bsum, boff, off);
    k_scan3<<<196, 512, 0, stream>>>(cur, boff, off);
    hipMemsetAsync(cur, 0, (size_t)NNODES * 4, stream);
    k_fill<<<NEDGES / 256, 256, 0, stream>>>(srcv, dstv, off, cur, adj);

    const int GB = (NNODES + 127) / 128;  // 782
    for (int i = 0; i < NLAYERS; i++) {
        hipMemsetAsync(stats, 0, 512 * 4, stream);
        k_agg<<<NNODES / 8, 256, 0, stream>>>(h, hb, off, adj, zb);
        k_gemm1<<<GB, 256, 0, stream>>>(
            zb, WT + (size_t)i * 16384, b1 + i * HID, bufB, stats);
        k_finalize<<<1, 128, 0, stream>>>(stats, g1 + i * HID, be1 + i * HID, scale1, shift1);
        k_gemm2<<<GB, 256, 0, stream>>>(
            bufB, WT + (size_t)(5 + i) * 16384, b2 + i * HID, bufA, scale1, shift1, stats + 256);
        k_finalize<<<1, 128, 0, stream>>>(stats + 256, gbn + i * HID, bbn + i * HID, scale2, shift2);
        k_resid<<<NNODES * 128 / 4 / 256, 256, 0, stream>>>(h, hb, bufA, scale2, shift2);
    }

    // pooling + projection
    hipMemsetAsync(pooled, 0, (size_t)(NGRAPHS * HID + NGRAPHS) * 4, stream);
    k_counts<<<1, 64, 0, stream>>>(batch, gcnt);
    k_pool<<<(NNODES + 127) / 128, 256, 0, stream>>>(h, batch, pooled);
    k_proj<<<NGRAPHS, 256, 0, stream>>>(pooled, gcnt, wp, bp, gemb);
}

// Round 4
// 1340.146 us; speedup vs baseline: 1.9023x; 1.1908x over previous
//
#include <hip/hip_runtime.h>

#define NNODES 100000
#define NEDGES 1600000
#define NGRAPHS 64
#define HID 128
#define OUTD 256
#define NLAYERS 5
#define BN_EPS 1e-5f

typedef __attribute__((ext_vector_type(8))) short short8;
typedef __attribute__((ext_vector_type(4))) float f32x4;

__device__ inline unsigned short f2b(float f) {
    union { float f; unsigned int u; } a; a.f = f;
    unsigned int u = a.u;
    return (unsigned short)((u + 0x7FFF + ((u >> 16) & 1)) >> 16);  // RNE
}
__device__ inline float b2f(unsigned short b) {
    union { unsigned int u; float f; } a; a.u = ((unsigned int)b) << 16;
    return a.f;
}

// ---------------- init: h = x (fp32) and hb = bf16(x) ----------------
__global__ void k_init(const float* __restrict__ x, float* __restrict__ h,
                       ushort* __restrict__ hb) {
    int i = blockIdx.x * 256 + threadIdx.x;  // float4 index
    float4 v = ((const float4*)x)[i];
    ((float4*)h)[i] = v;
    ushort4 o;
    o.x = f2b(v.x); o.y = f2b(v.y); o.z = f2b(v.z); o.w = f2b(v.w);
    ((ushort4*)hb)[i] = o;
}

// ---------------- CSR build ----------------
__global__ void k_hist(const int* __restrict__ dstv, int* __restrict__ deg) {
    int e = blockIdx.x * 256 + threadIdx.x;
    if (e < NEDGES) atomicAdd(&deg[dstv[e]], 1);
}

__global__ void k_scan1(const int* __restrict__ deg, int* __restrict__ bsum) {
    __shared__ int lds[512];
    int t = threadIdx.x, idx = blockIdx.x * 512 + t;
    lds[t] = (idx < NNODES) ? deg[idx] : 0;
    __syncthreads();
    for (int o = 256; o > 0; o >>= 1) {
        if (t < o) lds[t] += lds[t + o];
        __syncthreads();
    }
    if (t == 0) bsum[blockIdx.x] = lds[0];
}

__global__ void k_scan2(const int* __restrict__ bsum, int* __restrict__ boff,
                        int* __restrict__ off) {
    __shared__ int lds[256];
    int t = threadIdx.x;
    int v = (t < 196) ? bsum[t] : 0;
    lds[t] = v;
    __syncthreads();
    for (int o = 1; o < 256; o <<= 1) {
        int u = (t >= o) ? lds[t - o] : 0;
        __syncthreads();
        lds[t] += u;
        __syncthreads();
    }
    if (t < 196) boff[t] = lds[t] - v;  // exclusive
    if (t == 0) off[NNODES] = NEDGES;
}

__global__ void k_scan3(const int* __restrict__ deg, const int* __restrict__ boff,
                        int* __restrict__ off) {
    __shared__ int lds[512];
    int t = threadIdx.x, idx = blockIdx.x * 512 + t;
    int v = (idx < NNODES) ? deg[idx] : 0;
    lds[t] = v;
    __syncthreads();
    for (int o = 1; o < 512; o <<= 1) {
        int u = (t >= o) ? lds[t - o] : 0;
        __syncthreads();
        lds[t] += u;
        __syncthreads();
    }
    if (idx < NNODES) off[idx] = boff[blockIdx.x] + (lds[t] - v);
}

__global__ void k_fill(const int* __restrict__ srcv, const int* __restrict__ dstv,
                       const int* __restrict__ off, int* __restrict__ cur,
                       int* __restrict__ adj) {
    int e = blockIdx.x * 256 + threadIdx.x;
    if (e < NEDGES) {
        int d = dstv[e];
        int p = atomicAdd(&cur[d], 1);
        adj[off[d] + p] = srcv[e];
    }
}

// ---------------- W transpose to bf16 (all 10 matrices, once) ----------------
__global__ void k_wt(const float* __restrict__ w1, const float* __restrict__ w2,
                     unsigned short* __restrict__ WT) {
    int t = blockIdx.x * 256 + threadIdx.x;
    int mat = t >> 14;
    int rem = t & 16383;
    int k = rem >> 7, n = rem & 127;
    const float* src = (mat < 5) ? &w1[(size_t)mat * 16384] : &w2[(size_t)(mat - 5) * 16384];
    WT[(size_t)mat * 16384 + n * 128 + k] = f2b(src[k * 128 + n]);
}

// ---------------- aggregation: zb = bf16(hb_self + sum_nbr hb) ----------------
__global__ void k_agg(const ushort* __restrict__ hb, const int* __restrict__ off,
                      const int* __restrict__ adj, ushort* __restrict__ zb) {
    int tid = threadIdx.x;
    int node = blockIdx.x * 8 + (tid >> 5);
    int d4 = tid & 31;
    const ushort4* hb4 = (const ushort4*)hb;
    ushort4 sv = hb4[(size_t)node * 32 + d4];
    float4 v = make_float4(b2f(sv.x), b2f(sv.y), b2f(sv.z), b2f(sv.w));
    int e0 = off[node], e1 = off[node + 1];
    int e = e0;
    // 4-edge unroll: 4 independent gathers in flight
    for (; e + 4 <= e1; e += 4) {
        int s0 = adj[e], s1 = adj[e + 1], s2 = adj[e + 2], s3 = adj[e + 3];
        ushort4 u0 = hb4[(size_t)s0 * 32 + d4];
        ushort4 u1 = hb4[(size_t)s1 * 32 + d4];
        ushort4 u2 = hb4[(size_t)s2 * 32 + d4];
        ushort4 u3 = hb4[(size_t)s3 * 32 + d4];
        v.x += (b2f(u0.x) + b2f(u1.x)) + (b2f(u2.x) + b2f(u3.x));
        v.y += (b2f(u0.y) + b2f(u1.y)) + (b2f(u2.y) + b2f(u3.y));
        v.z += (b2f(u0.z) + b2f(u1.z)) + (b2f(u2.z) + b2f(u3.z));
        v.w += (b2f(u0.w) + b2f(u1.w)) + (b2f(u2.w) + b2f(u3.w));
    }
    for (; e < e1; e++) {
        int s = adj[e];
        ushort4 u = hb4[(size_t)s * 32 + d4];
        v.x += b2f(u.x); v.y += b2f(u.y); v.z += b2f(u.z); v.w += b2f(u.w);
    }
    ushort4 o;
    o.x = f2b(v.x); o.y = f2b(v.y); o.z = f2b(v.z); o.w = f2b(v.w);
    ((ushort4*)zb)[(size_t)node * 32 + d4] = o;
}

// ---------------- GEMM1: tb = bf16(zb @ W + bias), stats(fp32 t) -------------
__global__ __launch_bounds__(256) void k_gemm1(
    const ushort* __restrict__ A, const unsigned short* __restrict__ WT,
    const float* __restrict__ bias, ushort* __restrict__ C,
    float* __restrict__ stats) {
    __shared__ float lstat[256];
    int tid = threadIdx.x;
    int wave = tid >> 6;
    int lane = tid & 63;
    int q = lane >> 4;
    int l16 = lane & 15;
    int rowbase = blockIdx.x * 128 + wave * 32;

    f32x4 acc[2][8];
#pragma unroll
    for (int rt = 0; rt < 2; rt++)
#pragma unroll
        for (int nt = 0; nt < 8; nt++) acc[rt][nt] = (f32x4){0.f, 0.f, 0.f, 0.f};

    for (int kc = 0; kc < 4; kc++) {
        int k0 = kc * 32 + q * 8;
        short8 bf[8];
#pragma unroll
        for (int nt = 0; nt < 8; nt++)
            bf[nt] = *(const short8*)&WT[(size_t)(nt * 16 + l16) * 128 + k0];
#pragma unroll
        for (int rt = 0; rt < 2; rt++) {
            int row = rowbase + rt * 16 + l16;
            if (row >= NNODES) row = NNODES - 1;
            short8 av = *(const short8*)&A[(size_t)row * 128 + k0];
#pragma unroll
            for (int nt = 0; nt < 8; nt++)
                acc[rt][nt] = __builtin_amdgcn_mfma_f32_16x16x32_bf16(
                    av, bf[nt], acc[rt][nt], 0, 0, 0);
        }
    }

    lstat[tid] = 0.f;
    __syncthreads();
#pragma unroll
    for (int nt = 0; nt < 8; nt++) {
        float b = bias[nt * 16 + l16];
        float csum = 0.f, csq = 0.f;
#pragma unroll
        for (int rt = 0; rt < 2; rt++) {
            int rb = rowbase + rt * 16 + q * 4;
#pragma unroll
            for (int r = 0; r < 4; r++) {
                int row = rb + r;
                if (row < NNODES) {
                    float v = acc[rt][nt][r] + b;
                    C[(size_t)row * 128 + nt * 16 + l16] = f2b(v);
                    csum += v; csq += v * v;
                }
            }
        }
        csum += __shfl_xor(csum, 16, 64); csq += __shfl_xor(csq, 16, 64);
        csum += __shfl_xor(csum, 32, 64); csq += __shfl_xor(csq, 32, 64);
        if (q == 0) {
            atomicAdd(&lstat[nt * 16 + l16], csum);
            atomicAdd(&lstat[128 + nt * 16 + l16], csq);
        }
    }
    __syncthreads();
    atomicAdd(&stats[tid], lstat[tid]);
}

// --------- GEMM2: t2b = bf16(relu(BN1(tb)) @ W + bias), stats(fp32 t2) -------
// BN1 scale/shift computed per block from stats slice (no separate finalize).
__global__ __launch_bounds__(256) void k_gemm2(
    const ushort* __restrict__ A, const unsigned short* __restrict__ WT,
    const float* __restrict__ bias, ushort* __restrict__ C,
    const float* __restrict__ statsIn, const float* __restrict__ gamma,
    const float* __restrict__ beta, float* __restrict__ stats) {
    __shared__ float lstat[256];
    __shared__ float s_sc[128], s_sh[128];
    int tid = threadIdx.x;
    if (tid < 128) {
        float m = statsIn[tid] * (1.f / NNODES);
        float var = statsIn[128 + tid] * (1.f / NNODES) - m * m;
        float sc = gamma[tid] * rsqrtf(var + BN_EPS);
        s_sc[tid] = sc;
        s_sh[tid] = beta[tid] - m * sc;
    }
    __syncthreads();

    int wave = tid >> 6;
    int lane = tid & 63;
    int q = lane >> 4;
    int l16 = lane & 15;
    int rowbase = blockIdx.x * 128 + wave * 32;

    f32x4 acc[2][8];
#pragma unroll
    for (int rt = 0; rt < 2; rt++)
#pragma unroll
        for (int nt = 0; nt < 8; nt++) acc[rt][nt] = (f32x4){0.f, 0.f, 0.f, 0.f};

    for (int kc = 0; kc < 4; kc++) {
        int k0 = kc * 32 + q * 8;
        short8 bf[8];
#pragma unroll
        for (int nt = 0; nt < 8; nt++)
            bf[nt] = *(const short8*)&WT[(size_t)(nt * 16 + l16) * 128 + k0];

        float4 s0 = *(const float4*)&s_sc[k0];
        float4 s1 = *(const float4*)&s_sc[k0 + 4];
        float4 t0 = *(const float4*)&s_sh[k0];
        float4 t1 = *(const float4*)&s_sh[k0 + 4];
        float scl[8] = {s0.x, s0.y, s0.z, s0.w, s1.x, s1.y, s1.z, s1.w};
        float shf[8] = {t0.x, t0.y, t0.z, t0.w, t1.x, t1.y, t1.z, t1.w};
#pragma unroll
        for (int rt = 0; rt < 2; rt++) {
            int row = rowbase + rt * 16 + l16;
            if (row >= NNODES) row = NNODES - 1;
            union { short8 s; unsigned short u[8]; } in, cv;
            in.s = *(const short8*)&A[(size_t)row * 128 + k0];
#pragma unroll
            for (int j = 0; j < 8; j++) {
                float f = fmaxf(b2f(in.u[j]) * scl[j] + shf[j], 0.f);
                cv.u[j] = f2b(f);
            }
#pragma unroll
            for (int nt = 0; nt < 8; nt++)
                acc[rt][nt] = __builtin_amdgcn_mfma_f32_16x16x32_bf16(
                    cv.s, bf[nt], acc[rt][nt], 0, 0, 0);
        }
    }

    lstat[tid] = 0.f;
    __syncthreads();
#pragma unroll
    for (int nt = 0; nt < 8; nt++) {
        float b = bias[nt * 16 + l16];
        float csum = 0.f, csq = 0.f;
#pragma unroll
        for (int rt = 0; rt < 2; rt++) {
            int rb = rowbase + rt * 16 + q * 4;
#pragma unroll
            for (int r = 0; r < 4; r++) {
                int row = rb + r;
                if (row < NNODES) {
                    float v = acc[rt][nt][r] + b;
                    C[(size_t)row * 128 + nt * 16 + l16] = f2b(v);
                    csum += v; csq += v * v;
                }
            }
        }
        csum += __shfl_xor(csum, 16, 64); csq += __shfl_xor(csq, 16, 64);
        csum += __shfl_xor(csum, 32, 64); csq += __shfl_xor(csq, 32, 64);
        if (q == 0) {
            atomicAdd(&lstat[nt * 16 + l16], csum);
            atomicAdd(&lstat[128 + nt * 16 + l16], csq);
        }
    }
    __syncthreads();
    atomicAdd(&stats[tid], lstat[tid]);
}

// ---- resid: h += relu(BN2(t2b)); hb = bf16(h). BN2 from stats slice. --------
__global__ void k_resid(float* __restrict__ h, ushort* __restrict__ hb,
                        const ushort* __restrict__ t2b,
                        const float* __restrict__ statsIn,
                        const float* __restrict__ gamma, const float* __restrict__ beta) {
    __shared__ float s_sc[128], s_sh[128];
    int tid = threadIdx.x;
    if (tid < 128) {
        float m = statsIn[tid] * (1.f / NNODES);
        float var = statsIn[128 + tid] * (1.f / NNODES) - m * m;
        float sc = gamma[tid] * rsqrtf(var + BN_EPS);
        s_sc[tid] = sc;
        s_sh[tid] = beta[tid] - m * sc;
    }
    __syncthreads();
    int i = blockIdx.x * 256 + tid;
    int c4 = (i & 31) * 4;
    float4 sc = *(const float4*)&s_sc[c4];
    float4 sh = *(const float4*)&s_sh[c4];
    ushort4 t = ((const ushort4*)t2b)[i];
    float4 hv = ((float4*)h)[i];
    hv.x += fmaxf(b2f(t.x) * sc.x + sh.x, 0.f);
    hv.y += fmaxf(b2f(t.y) * sc.y + sh.y, 0.f);
    hv.z += fmaxf(b2f(t.z) * sc.z + sh.z, 0.f);
    hv.w += fmaxf(b2f(t.w) * sc.w + sh.w, 0.f);
    ((float4*)h)[i] = hv;
    ushort4 o;
    o.x = f2b(hv.x); o.y = f2b(hv.y); o.z = f2b(hv.z); o.w = f2b(hv.w);
    ((ushort4*)hb)[i] = o;
}

// ---------------- pooling + projection ----------------
__global__ void k_counts(const int* __restrict__ batch, float* __restrict__ cnt) {
    int g = threadIdx.x;
    if (g >= NGRAPHS) return;
    auto lb = [&](int key) {
        int lo = 0, hi = NNODES;
        while (lo < hi) {
            int mid = (lo + hi) >> 1;
            if (batch[mid] < key) lo = mid + 1; else hi = mid;
        }
        return lo;
    };
    cnt[g] = (float)(lb(g + 1) - lb(g));
}

__global__ void k_pool(const float* __restrict__ h, const int* __restrict__ batch,
                       float* __restrict__ pooled) {
    __shared__ float4 red[256];
    int t = threadIdx.x;
    int d4 = t & 31, sub = t >> 5;
    int n0 = blockIdx.x * 128;
    if (n0 >= NNODES) return;
    int n1 = n0 + 128; if (n1 > NNODES) n1 = NNODES;
    int glo = batch[n0], ghi = batch[n1 - 1];
    for (int g = glo; g <= ghi; g++) {
        float4 acc = make_float4(0.f, 0.f, 0.f, 0.f);
        for (int r = n0 + sub; r < n1; r += 8) {
            if (batch[r] == g) {
                float4 v = ((const float4*)h)[(size_t)r * 32 + d4];
                acc.x += v.x; acc.y += v.y; acc.z += v.z; acc.w += v.w;
            }
        }
        red[t] = acc;
        __syncthreads();
        if (sub < 4) {
            float4 o = red[t + 128];
            red[t].x += o.x; red[t].y += o.y; red[t].z += o.z; red[t].w += o.w;
        }
        __syncthreads();
        if (sub < 2) {
            float4 o = red[t + 64];
            red[t].x += o.x; red[t].y += o.y; red[t].z += o.z; red[t].w += o.w;
        }
        __syncthreads();
        if (sub == 0) {
            float4 o = red[t + 32];
            float4 a = red[t];
            a.x += o.x; a.y += o.y; a.z += o.z; a.w += o.w;
            atomicAdd(&pooled[g * 128 + d4 * 4 + 0], a.x);
            atomicAdd(&pooled[g * 128 + d4 * 4 + 1], a.y);
            atomicAdd(&pooled[g * 128 + d4 * 4 + 2], a.z);
            atomicAdd(&pooled[g * 128 + d4 * 4 + 3], a.w);
        }
        __syncthreads();
    }
}

__global__ void k_proj(const float* __restrict__ pooled, const float* __restrict__ cnt,
                       const float* __restrict__ wp, const float* __restrict__ bp,
                       float* __restrict__ out) {
    __shared__ float prow[128];
    int g = blockIdx.x, c = threadIdx.x;
    if (c < 128) prow[c] = pooled[g * 128 + c] / fmaxf(cnt[g], 1.f);
    __syncthreads();
    float acc = bp[c];
    for (int k = 0; k < 128; k++) acc += prow[k] * wp[k * 256 + c];
    out[g * 256 + c] = acc;
}

extern "C" void kernel_launch(void* const* d_in, const int* in_sizes, int n_in,
                              void* d_out, int out_size, void* d_ws, size_t ws_size,
                              hipStream_t stream) {
    const float* x    = (const float*)d_in[0];
    const int*   eidx = (const int*)d_in[1];
    const int*   batch= (const int*)d_in[2];
    const float* w1   = (const float*)d_in[3];
    const float* b1   = (const float*)d_in[4];
    const float* g1   = (const float*)d_in[5];
    const float* be1  = (const float*)d_in[6];
    const float* w2   = (const float*)d_in[7];
    const float* b2   = (const float*)d_in[8];
    const float* gbn  = (const float*)d_in[9];
    const float* bbn  = (const float*)d_in[10];
    const float* wp   = (const float*)d_in[11];
    const float* bp   = (const float*)d_in[12];

    float* out  = (float*)d_out;
    float* gemb = out;                          // [64,256]
    float* h    = out + (size_t)NGRAPHS * OUTD; // node_emb lives in d_out

    char* w = (char*)d_ws;
    ushort* hb   = (ushort*)w; w += (size_t)NNODES * 128 * 2; // bf16 mirror of h
    ushort* zb   = (ushort*)w; w += (size_t)NNODES * 128 * 2; // bf16 z
    ushort* tb   = (ushort*)w; w += (size_t)NNODES * 128 * 2; // bf16 t
    ushort* t2b  = (ushort*)w; w += (size_t)NNODES * 128 * 2; // bf16 t2
    int*   off   = (int*)w;   w += (size_t)(NNODES + 8) * 4;
    int*   cur   = (int*)w;   w += (size_t)NNODES * 4;
    int*   adj   = (int*)w;   w += (size_t)NEDGES * 4;
    unsigned short* WT = (unsigned short*)w; w += (size_t)10 * 16384 * 2;
    int*   bsum  = (int*)w;   w += 256 * 4;
    int*   boff  = (int*)w;   w += 256 * 4;
    float* statsAll = (float*)w; w += 10 * 256 * 4;  // per-GEMM slices
    float* pooled= (float*)w; w += (size_t)NGRAPHS * HID * 4;
    float* gcnt  = (float*)w; w += NGRAPHS * 4;

    const int* srcv = eidx;
    const int* dstv = eidx + NEDGES;

    // h = x, hb = bf16(x)
    k_init<<<NNODES * 32 / 256, 256, 0, stream>>>(x, h, hb);

    // W transposes (bf16), once
    k_wt<<<640, 256, 0, stream>>>(w1, w2, WT);

    // zero all stats slices + pooled in one shot (contiguous)
    hipMemsetAsync(statsAll, 0,
                   (10 * 256 + NGRAPHS * HID + NGRAPHS) * 4, stream);

    // CSR build
    hipMemsetAsync(cur, 0, (size_t)NNODES * 4, stream);
    k_hist<<<NEDGES / 256, 256, 0, stream>>>(dstv, cur);
    k_scan1<<<196, 512, 0, stream>>>(cur, bsum);
    k_scan2<<<1, 256, 0, stream>>>(bsum, boff, off);
    k_scan3<<<196, 512, 0, stream>>>(cur, boff, off);
    hipMemsetAsync(cur, 0, (size_t)NNODES * 4, stream);
    k_fill<<<NEDGES / 256, 256, 0, stream>>>(srcv, dstv, off, cur, adj);

    const int GB = (NNODES + 127) / 128;  // 782
    for (int i = 0; i < NLAYERS; i++) {
        float* st1 = statsAll + (size_t)(2 * i) * 256;
        float* st2 = statsAll + (size_t)(2 * i + 1) * 256;
        k_agg<<<NNODES / 8, 256, 0, stream>>>(hb, off, adj, zb);
        k_gemm1<<<GB, 256, 0, stream>>>(
            zb, WT + (size_t)i * 16384, b1 + i * HID, tb, st1);
        k_gemm2<<<GB, 256, 0, stream>>>(
            tb, WT + (size_t)(5 + i) * 16384, b2 + i * HID, t2b,
            st1, g1 + i * HID, be1 + i * HID, st2);
        k_resid<<<NNODES * 128 / 4 / 256, 256, 0, stream>>>(
            h, hb, t2b, st2, gbn + i * HID, bbn + i * HID);
    }

    // pooling + projection
    k_counts<<<1, 64, 0, stream>>>(batch, gcnt);
    k_pool<<<(NNODES + 127) / 128, 256, 0, stream>>>(h, batch, pooled);
    k_proj<<<NGRAPHS, 256, 0, stream>>>(pooled, gcnt, wp, bp, gemb);
}

// Round 5
// 1310.806 us; speedup vs baseline: 1.9448x; 1.0224x over previous
//
#include <hip/hip_runtime.h>

#define NNODES 100000
#define NEDGES 1600000
#define NGRAPHS 64
#define HID 128
#define OUTD 256
#define NLAYERS 5
#define BN_EPS 1e-5f
#define NBUCK 196          // ceil(NNODES/512)
#define FILL_BLOCKS 391    // ceil(NEDGES/4096)

typedef __attribute__((ext_vector_type(8))) short short8;
typedef __attribute__((ext_vector_type(4))) float f32x4;

__device__ inline unsigned short f2b(float f) {
    union { float f; unsigned int u; } a; a.f = f;
    unsigned int u = a.u;
    return (unsigned short)((u + 0x7FFF + ((u >> 16) & 1)) >> 16);  // RNE
}
__device__ inline float b2f(unsigned short b) {
    union { unsigned int u; float f; } a; a.u = ((unsigned int)b) << 16;
    return a.f;
}

// ---------------- init: h = x (fp32) and hb = bf16(x) ----------------
__global__ void k_init(const float* __restrict__ x, float* __restrict__ h,
                       ushort* __restrict__ hb) {
    int i = blockIdx.x * 256 + threadIdx.x;  // float4 index
    float4 v = ((const float4*)x)[i];
    ((float4*)h)[i] = v;
    ushort4 o;
    o.x = f2b(v.x); o.y = f2b(v.y); o.z = f2b(v.z); o.w = f2b(v.w);
    ((ushort4*)hb)[i] = o;
}

// ---------------- CSR build ----------------
__global__ void k_hist(const int* __restrict__ dstv, int* __restrict__ deg) {
    int e = blockIdx.x * 256 + threadIdx.x;
    if (e < NEDGES) atomicAdd(&deg[dstv[e]], 1);
}

__global__ void k_scan1(const int* __restrict__ deg, int* __restrict__ bsum) {
    __shared__ int lds[512];
    int t = threadIdx.x, idx = blockIdx.x * 512 + t;
    lds[t] = (idx < NNODES) ? deg[idx] : 0;
    __syncthreads();
    for (int o = 256; o > 0; o >>= 1) {
        if (t < o) lds[t] += lds[t + o];
        __syncthreads();
    }
    if (t == 0) bsum[blockIdx.x] = lds[0];
}

__global__ void k_scan2(const int* __restrict__ bsum, int* __restrict__ boff,
                        int* __restrict__ off) {
    __shared__ int lds[256];
    int t = threadIdx.x;
    int v = (t < 196) ? bsum[t] : 0;
    lds[t] = v;
    __syncthreads();
    for (int o = 1; o < 256; o <<= 1) {
        int u = (t >= o) ? lds[t - o] : 0;
        __syncthreads();
        lds[t] += u;
        __syncthreads();
    }
    if (t < 196) boff[t] = lds[t] - v;  // exclusive
    if (t == 0) off[NNODES] = NEDGES;
}

__global__ void k_scan3(const int* __restrict__ deg, const int* __restrict__ boff,
                        int* __restrict__ off) {
    __shared__ int lds[512];
    int t = threadIdx.x, idx = blockIdx.x * 512 + t;
    int v = (idx < NNODES) ? deg[idx] : 0;
    lds[t] = v;
    __syncthreads();
    for (int o = 1; o < 512; o <<= 1) {
        int u = (t >= o) ? lds[t - o] : 0;
        __syncthreads();
        lds[t] += u;
        __syncthreads();
    }
    if (idx < NNODES) off[idx] = boff[blockIdx.x] + (lds[t] - v);
}

// bcur[b] = off[b*512]  (bucket write frontier init)
__global__ void k_bsetup(const int* __restrict__ off, int* __restrict__ bcur) {
    int t = threadIdx.x;
    if (t < NBUCK) bcur[t] = off[t * 512];
}

// Phase 1: scatter (src<<9 | dst&511) into per-bucket regions, block-chunked.
__global__ __launch_bounds__(256) void k_fill1(
    const int* __restrict__ srcv, const int* __restrict__ dstv,
    int* __restrict__ bcur, unsigned int* __restrict__ packed) {
    __shared__ int hist[NBUCK];
    __shared__ int base[NBUCK];
    int tid = threadIdx.x;
    int e0 = blockIdx.x * 4096;
    for (int i = tid; i < NBUCK; i += 256) hist[i] = 0;
    __syncthreads();
#pragma unroll
    for (int i = 0; i < 16; i++) {
        int e = e0 + i * 256 + tid;
        if (e < NEDGES) atomicAdd(&hist[dstv[e] >> 9], 1);
    }
    __syncthreads();
    for (int i = tid; i < NBUCK; i += 256) {
        int c = hist[i];
        base[i] = c ? atomicAdd(&bcur[i], c) : 0;
        hist[i] = 0;
    }
    __syncthreads();
#pragma unroll
    for (int i = 0; i < 16; i++) {
        int e = e0 + i * 256 + tid;
        if (e < NEDGES) {
            int d = dstv[e];
            int b = d >> 9;
            int r = atomicAdd(&hist[b], 1);
            packed[base[b] + r] = ((unsigned int)srcv[e] << 9) | (unsigned int)(d & 511);
        }
    }
}

// Phase 2: one block per bucket; coalesced read, LDS cursors, local adj writes.
__global__ __launch_bounds__(256) void k_fill2(
    const unsigned int* __restrict__ packed, const int* __restrict__ off,
    int* __restrict__ adj) {
    __shared__ int cur[512];
    __shared__ int offL[512];
    int tid = threadIdx.x;
    int nbase = blockIdx.x * 512;
#pragma unroll
    for (int i = 0; i < 2; i++) {
        int t = tid + i * 256;
        cur[t] = 0;
        int n = nbase + t;
        offL[t] = (n < NNODES) ? off[n] : NEDGES;
    }
    __syncthreads();
    int nend = nbase + 512; if (nend > NNODES) nend = NNODES;
    int ebase = off[nbase];
    int eend = off[nend];
    for (int i = ebase + tid; i < eend; i += 256) {
        unsigned int p = packed[i];
        int src = (int)(p >> 9);
        int dl = (int)(p & 511);
        int r = atomicAdd(&cur[dl], 1);
        adj[offL[dl] + r] = src;
    }
}

// ---------------- W transpose to bf16 (all 10 matrices, once) ----------------
__global__ void k_wt(const float* __restrict__ w1, const float* __restrict__ w2,
                     unsigned short* __restrict__ WT) {
    int t = blockIdx.x * 256 + threadIdx.x;
    int mat = t >> 14;
    int rem = t & 16383;
    int k = rem >> 7, n = rem & 127;
    const float* src = (mat < 5) ? &w1[(size_t)mat * 16384] : &w2[(size_t)(mat - 5) * 16384];
    WT[(size_t)mat * 16384 + n * 128 + k] = f2b(src[k * 128 + n]);
}

// ---------------- aggregation: zb = bf16(hb_self + sum_nbr hb) ----------------
__global__ void k_agg(const ushort* __restrict__ hb, const int* __restrict__ off,
                      const int* __restrict__ adj, ushort* __restrict__ zb) {
    int tid = threadIdx.x;
    int node = blockIdx.x * 8 + (tid >> 5);
    int d4 = tid & 31;
    const ushort4* hb4 = (const ushort4*)hb;
    ushort4 sv = hb4[(size_t)node * 32 + d4];
    float4 v = make_float4(b2f(sv.x), b2f(sv.y), b2f(sv.z), b2f(sv.w));
    int e0 = off[node], e1 = off[node + 1];
    int e = e0;
    // 8-edge unroll: 8 independent gathers in flight
    for (; e + 8 <= e1; e += 8) {
        int s[8]; ushort4 u[8];
#pragma unroll
        for (int j = 0; j < 8; j++) s[j] = adj[e + j];
#pragma unroll
        for (int j = 0; j < 8; j++) u[j] = hb4[(size_t)s[j] * 32 + d4];
#pragma unroll
        for (int j = 0; j < 8; j++) {
            v.x += b2f(u[j].x); v.y += b2f(u[j].y);
            v.z += b2f(u[j].z); v.w += b2f(u[j].w);
        }
    }
    for (; e + 4 <= e1; e += 4) {
        int s0 = adj[e], s1 = adj[e + 1], s2 = adj[e + 2], s3 = adj[e + 3];
        ushort4 u0 = hb4[(size_t)s0 * 32 + d4];
        ushort4 u1 = hb4[(size_t)s1 * 32 + d4];
        ushort4 u2 = hb4[(size_t)s2 * 32 + d4];
        ushort4 u3 = hb4[(size_t)s3 * 32 + d4];
        v.x += (b2f(u0.x) + b2f(u1.x)) + (b2f(u2.x) + b2f(u3.x));
        v.y += (b2f(u0.y) + b2f(u1.y)) + (b2f(u2.y) + b2f(u3.y));
        v.z += (b2f(u0.z) + b2f(u1.z)) + (b2f(u2.z) + b2f(u3.z));
        v.w += (b2f(u0.w) + b2f(u1.w)) + (b2f(u2.w) + b2f(u3.w));
    }
    for (; e < e1; e++) {
        int s = adj[e];
        ushort4 u = hb4[(size_t)s * 32 + d4];
        v.x += b2f(u.x); v.y += b2f(u.y); v.z += b2f(u.z); v.w += b2f(u.w);
    }
    ushort4 o;
    o.x = f2b(v.x); o.y = f2b(v.y); o.z = f2b(v.z); o.w = f2b(v.w);
    ((ushort4*)zb)[(size_t)node * 32 + d4] = o;
}

// ---------------- GEMM1: tb = bf16(zb @ W + bias), stats(fp32 t) -------------
__global__ __launch_bounds__(256) void k_gemm1(
    const ushort* __restrict__ A, const unsigned short* __restrict__ WT,
    const float* __restrict__ bias, ushort* __restrict__ C,
    float* __restrict__ stats) {
    __shared__ float lstat[256];
    int tid = threadIdx.x;
    int wave = tid >> 6;
    int lane = tid & 63;
    int q = lane >> 4;
    int l16 = lane & 15;
    int rowbase = blockIdx.x * 128 + wave * 32;

    f32x4 acc[2][8];
#pragma unroll
    for (int rt = 0; rt < 2; rt++)
#pragma unroll
        for (int nt = 0; nt < 8; nt++) acc[rt][nt] = (f32x4){0.f, 0.f, 0.f, 0.f};

    for (int kc = 0; kc < 4; kc++) {
        int k0 = kc * 32 + q * 8;
        short8 bf[8];
#pragma unroll
        for (int nt = 0; nt < 8; nt++)
            bf[nt] = *(const short8*)&WT[(size_t)(nt * 16 + l16) * 128 + k0];
#pragma unroll
        for (int rt = 0; rt < 2; rt++) {
            int row = rowbase + rt * 16 + l16;
            if (row >= NNODES) row = NNODES - 1;
            short8 av = *(const short8*)&A[(size_t)row * 128 + k0];
#pragma unroll
            for (int nt = 0; nt < 8; nt++)
                acc[rt][nt] = __builtin_amdgcn_mfma_f32_16x16x32_bf16(
                    av, bf[nt], acc[rt][nt], 0, 0, 0);
        }
    }

    lstat[tid] = 0.f;
    __syncthreads();
#pragma unroll
    for (int nt = 0; nt < 8; nt++) {
        float b = bias[nt * 16 + l16];
        float csum = 0.f, csq = 0.f;
#pragma unroll
        for (int rt = 0; rt < 2; rt++) {
            int rb = rowbase + rt * 16 + q * 4;
#pragma unroll
            for (int r = 0; r < 4; r++) {
                int row = rb + r;
                if (row < NNODES) {
                    float v = acc[rt][nt][r] + b;
                    C[(size_t)row * 128 + nt * 16 + l16] = f2b(v);
                    csum += v; csq += v * v;
                }
            }
        }
        csum += __shfl_xor(csum, 16, 64); csq += __shfl_xor(csq, 16, 64);
        csum += __shfl_xor(csum, 32, 64); csq += __shfl_xor(csq, 32, 64);
        if (q == 0) {
            atomicAdd(&lstat[nt * 16 + l16], csum);
            atomicAdd(&lstat[128 + nt * 16 + l16], csq);
        }
    }
    __syncthreads();
    atomicAdd(&stats[tid], lstat[tid]);
}

// --------- GEMM2: t2b = bf16(relu(BN1(tb)) @ W + bias), stats(fp32 t2) -------
__global__ __launch_bounds__(256) void k_gemm2(
    const ushort* __restrict__ A, const unsigned short* __restrict__ WT,
    const float* __restrict__ bias, ushort* __restrict__ C,
    const float* __restrict__ statsIn, const float* __restrict__ gamma,
    const float* __restrict__ beta, float* __restrict__ stats) {
    __shared__ float lstat[256];
    __shared__ float s_sc[128], s_sh[128];
    int tid = threadIdx.x;
    if (tid < 128) {
        float m = statsIn[tid] * (1.f / NNODES);
        float var = statsIn[128 + tid] * (1.f / NNODES) - m * m;
        float sc = gamma[tid] * rsqrtf(var + BN_EPS);
        s_sc[tid] = sc;
        s_sh[tid] = beta[tid] - m * sc;
    }
    __syncthreads();

    int wave = tid >> 6;
    int lane = tid & 63;
    int q = lane >> 4;
    int l16 = lane & 15;
    int rowbase = blockIdx.x * 128 + wave * 32;

    f32x4 acc[2][8];
#pragma unroll
    for (int rt = 0; rt < 2; rt++)
#pragma unroll
        for (int nt = 0; nt < 8; nt++) acc[rt][nt] = (f32x4){0.f, 0.f, 0.f, 0.f};

    for (int kc = 0; kc < 4; kc++) {
        int k0 = kc * 32 + q * 8;
        short8 bf[8];
#pragma unroll
        for (int nt = 0; nt < 8; nt++)
            bf[nt] = *(const short8*)&WT[(size_t)(nt * 16 + l16) * 128 + k0];

        float4 s0 = *(const float4*)&s_sc[k0];
        float4 s1 = *(const float4*)&s_sc[k0 + 4];
        float4 t0 = *(const float4*)&s_sh[k0];
        float4 t1 = *(const float4*)&s_sh[k0 + 4];
        float scl[8] = {s0.x, s0.y, s0.z, s0.w, s1.x, s1.y, s1.z, s1.w};
        float shf[8] = {t0.x, t0.y, t0.z, t0.w, t1.x, t1.y, t1.z, t1.w};
#pragma unroll
        for (int rt = 0; rt < 2; rt++) {
            int row = rowbase + rt * 16 + l16;
            if (row >= NNODES) row = NNODES - 1;
            union { short8 s; unsigned short u[8]; } in, cv;
            in.s = *(const short8*)&A[(size_t)row * 128 + k0];
#pragma unroll
            for (int j = 0; j < 8; j++) {
                float f = fmaxf(b2f(in.u[j]) * scl[j] + shf[j], 0.f);
                cv.u[j] = f2b(f);
            }
#pragma unroll
            for (int nt = 0; nt < 8; nt++)
                acc[rt][nt] = __builtin_amdgcn_mfma_f32_16x16x32_bf16(
                    cv.s, bf[nt], acc[rt][nt], 0, 0, 0);
        }
    }

    lstat[tid] = 0.f;
    __syncthreads();
#pragma unroll
    for (int nt = 0; nt < 8; nt++) {
        float b = bias[nt * 16 + l16];
        float csum = 0.f, csq = 0.f;
#pragma unroll
        for (int rt = 0; rt < 2; rt++) {
            int rb = rowbase + rt * 16 + q * 4;
#pragma unroll
            for (int r = 0; r < 4; r++) {
                int row = rb + r;
                if (row < NNODES) {
                    float v = acc[rt][nt][r] + b;
                    C[(size_t)row * 128 + nt * 16 + l16] = f2b(v);
                    csum += v; csq += v * v;
                }
            }
        }
        csum += __shfl_xor(csum, 16, 64); csq += __shfl_xor(csq, 16, 64);
        csum += __shfl_xor(csum, 32, 64); csq += __shfl_xor(csq, 32, 64);
        if (q == 0) {
            atomicAdd(&lstat[nt * 16 + l16], csum);
            atomicAdd(&lstat[128 + nt * 16 + l16], csq);
        }
    }
    __syncthreads();
    atomicAdd(&stats[tid], lstat[tid]);
}

// ---- resid: h += relu(BN2(t2b)); hb = bf16(h). BN2 from stats slice. --------
__global__ void k_resid(float* __restrict__ h, ushort* __restrict__ hb,
                        const ushort* __restrict__ t2b,
                        const float* __restrict__ statsIn,
                        const float* __restrict__ gamma, const float* __restrict__ beta) {
    __shared__ float s_sc[128], s_sh[128];
    int tid = threadIdx.x;
    if (tid < 128) {
        float m = statsIn[tid] * (1.f / NNODES);
        float var = statsIn[128 + tid] * (1.f / NNODES) - m * m;
        float sc = gamma[tid] * rsqrtf(var + BN_EPS);
        s_sc[tid] = sc;
        s_sh[tid] = beta[tid] - m * sc;
    }
    __syncthreads();
    int i = blockIdx.x * 256 + tid;
    int c4 = (i & 31) * 4;
    float4 sc = *(const float4*)&s_sc[c4];
    float4 sh = *(const float4*)&s_sh[c4];
    ushort4 t = ((const ushort4*)t2b)[i];
    float4 hv = ((float4*)h)[i];
    hv.x += fmaxf(b2f(t.x) * sc.x + sh.x, 0.f);
    hv.y += fmaxf(b2f(t.y) * sc.y + sh.y, 0.f);
    hv.z += fmaxf(b2f(t.z) * sc.z + sh.z, 0.f);
    hv.w += fmaxf(b2f(t.w) * sc.w + sh.w, 0.f);
    ((float4*)h)[i] = hv;
    ushort4 o;
    o.x = f2b(hv.x); o.y = f2b(hv.y); o.z = f2b(hv.z); o.w = f2b(hv.w);
    ((ushort4*)hb)[i] = o;
}

// ---------------- pooling + projection ----------------
__global__ void k_counts(const int* __restrict__ batch, float* __restrict__ cnt) {
    int g = threadIdx.x;
    if (g >= NGRAPHS) return;
    auto lb = [&](int key) {
        int lo = 0, hi = NNODES;
        while (lo < hi) {
            int mid = (lo + hi) >> 1;
            if (batch[mid] < key) lo = mid + 1; else hi = mid;
        }
        return lo;
    };
    cnt[g] = (float)(lb(g + 1) - lb(g));
}

__global__ void k_pool(const float* __restrict__ h, const int* __restrict__ batch,
                       float* __restrict__ pooled) {
    __shared__ float4 red[256];
    int t = threadIdx.x;
    int d4 = t & 31, sub = t >> 5;
    int n0 = blockIdx.x * 128;
    if (n0 >= NNODES) return;
    int n1 = n0 + 128; if (n1 > NNODES) n1 = NNODES;
    int glo = batch[n0], ghi = batch[n1 - 1];
    for (int g = glo; g <= ghi; g++) {
        float4 acc = make_float4(0.f, 0.f, 0.f, 0.f);
        for (int r = n0 + sub; r < n1; r += 8) {
            if (batch[r] == g) {
                float4 v = ((const float4*)h)[(size_t)r * 32 + d4];
                acc.x += v.x; acc.y += v.y; acc.z += v.z; acc.w += v.w;
            }
        }
        red[t] = acc;
        __syncthreads();
        if (sub < 4) {
            float4 o = red[t + 128];
            red[t].x += o.x; red[t].y += o.y; red[t].z += o.z; red[t].w += o.w;
        }
        __syncthreads();
        if (sub < 2) {
            float4 o = red[t + 64];
            red[t].x += o.x; red[t].y += o.y; red[t].z += o.z; red[t].w += o.w;
        }
        __syncthreads();
        if (sub == 0) {
            float4 o = red[t + 32];
            float4 a = red[t];
            a.x += o.x; a.y += o.y; a.z += o.z; a.w += o.w;
            atomicAdd(&pooled[g * 128 + d4 * 4 + 0], a.x);
            atomicAdd(&pooled[g * 128 + d4 * 4 + 1], a.y);
            atomicAdd(&pooled[g * 128 + d4 * 4 + 2], a.z);
            atomicAdd(&pooled[g * 128 + d4 * 4 + 3], a.w);
        }
        __syncthreads();
    }
}

__global__ void k_proj(const float* __restrict__ pooled, const float* __restrict__ cnt,
                       const float* __restrict__ wp, const float* __restrict__ bp,
                       float* __restrict__ out) {
    __shared__ float prow[128];
    int g = blockIdx.x, c = threadIdx.x;
    if (c < 128) prow[c] = pooled[g * 128 + c] / fmaxf(cnt[g], 1.f);
    __syncthreads();
    float acc = bp[c];
    for (int k = 0; k < 128; k++) acc += prow[k] * wp[k * 256 + c];
    out[g * 256 + c] = acc;
}

extern "C" void kernel_launch(void* const* d_in, const int* in_sizes, int n_in,
                              void* d_out, int out_size, void* d_ws, size_t ws_size,
                              hipStream_t stream) {
    const float* x    = (const float*)d_in[0];
    const int*   eidx = (const int*)d_in[1];
    const int*   batch= (const int*)d_in[2];
    const float* w1   = (const float*)d_in[3];
    const float* b1   = (const float*)d_in[4];
    const float* g1   = (const float*)d_in[5];
    const float* be1  = (const float*)d_in[6];
    const float* w2   = (const float*)d_in[7];
    const float* b2   = (const float*)d_in[8];
    const float* gbn  = (const float*)d_in[9];
    const float* bbn  = (const float*)d_in[10];
    const float* wp   = (const float*)d_in[11];
    const float* bp   = (const float*)d_in[12];

    float* out  = (float*)d_out;
    float* gemb = out;                          // [64,256]
    float* h    = out + (size_t)NGRAPHS * OUTD; // node_emb lives in d_out

    char* w = (char*)d_ws;
    ushort* hb   = (ushort*)w; w += (size_t)NNODES * 128 * 2; // bf16 mirror of h
    ushort* zb   = (ushort*)w; w += (size_t)NNODES * 128 * 2; // bf16 z
    ushort* tb   = (ushort*)w; w += (size_t)NNODES * 128 * 2; // bf16 t
    ushort* t2b  = (ushort*)w; w += (size_t)NNODES * 128 * 2; // bf16 t2
    int*   off   = (int*)w;   w += (size_t)(NNODES + 8) * 4;
    int*   cur   = (int*)w;   w += (size_t)NNODES * 4;        // deg
    int*   adj   = (int*)w;   w += (size_t)NEDGES * 4;
    unsigned short* WT = (unsigned short*)w; w += (size_t)10 * 16384 * 2;
    int*   bsum  = (int*)w;   w += 256 * 4;
    int*   boff  = (int*)w;   w += 256 * 4;
    int*   bcur  = (int*)w;   w += 256 * 4;
    float* statsAll = (float*)w; w += 10 * 256 * 4;  // per-GEMM slices
    float* pooled= (float*)w; w += (size_t)NGRAPHS * HID * 4;
    float* gcnt  = (float*)w; w += NGRAPHS * 4;

    // packed edge buffer aliases tb (dead until layer loop)
    unsigned int* packed = (unsigned int*)tb;

    const int* srcv = eidx;
    const int* dstv = eidx + NEDGES;

    // h = x, hb = bf16(x)
    k_init<<<NNODES * 32 / 256, 256, 0, stream>>>(x, h, hb);

    // W transposes (bf16), once
    k_wt<<<640, 256, 0, stream>>>(w1, w2, WT);

    // zero stats slices + pooled + gcnt in one shot (contiguous)
    hipMemsetAsync(statsAll, 0,
                   (10 * 256 + NGRAPHS * HID + NGRAPHS) * 4, stream);

    // CSR build: hist -> scan -> bucket scatter -> bucket-local fill
    hipMemsetAsync(cur, 0, (size_t)NNODES * 4, stream);
    k_hist<<<NEDGES / 256, 256, 0, stream>>>(dstv, cur);
    k_scan1<<<196, 512, 0, stream>>>(cur, bsum);
    k_scan2<<<1, 256, 0, stream>>>(bsum, boff, off);
    k_scan3<<<196, 512, 0, stream>>>(cur, boff, off);
    k_bsetup<<<1, 256, 0, stream>>>(off, bcur);
    k_fill1<<<FILL_BLOCKS, 256, 0, stream>>>(srcv, dstv, bcur, packed);
    k_fill2<<<NBUCK, 256, 0, stream>>>(packed, off, adj);

    const int GB = (NNODES + 127) / 128;  // 782
    for (int i = 0; i < NLAYERS; i++) {
        float* st1 = statsAll + (size_t)(2 * i) * 256;
        float* st2 = statsAll + (size_t)(2 * i + 1) * 256;
        k_agg<<<NNODES / 8, 256, 0, stream>>>(hb, off, adj, zb);
        k_gemm1<<<GB, 256, 0, stream>>>(
            zb, WT + (size_t)i * 16384, b1 + i * HID, tb, st1);
        k_gemm2<<<GB, 256, 0, stream>>>(
            tb, WT + (size_t)(5 + i) * 16384, b2 + i * HID, t2b,
            st1, g1 + i * HID, be1 + i * HID, st2);
        k_resid<<<NNODES * 128 / 4 / 256, 256, 0, stream>>>(
            h, hb, t2b, st2, gbn + i * HID, bbn + i * HID);
    }

    // pooling + projection
    k_counts<<<1, 64, 0, stream>>>(batch, gcnt);
    k_pool<<<(NNODES + 127) / 128, 256, 0, stream>>>(h, batch, pooled);
    k_proj<<<NGRAPHS, 256, 0, stream>>>(pooled, gcnt, wp, bp, gemb);
}

// Round 6
// 1061.806 us; speedup vs baseline: 2.4009x; 1.2345x over previous
//
#include <hip/hip_runtime.h>

#define NNODES 100000
#define NEDGES 1600000
#define NGRAPHS 64
#define HID 128
#define OUTD 256
#define NLAYERS 5
#define BN_EPS 1e-5f
#define NBUCK 196          // ceil(NNODES/512)
#define BUCKCAP 9216       // avg 8192 edges/bucket + 11 sigma
#define FILL_BLOCKS 391    // ceil(NEDGES/4096)
#define NREP 8             // stats atomic replicas

typedef __attribute__((ext_vector_type(8))) short short8;
typedef __attribute__((ext_vector_type(4))) float f32x4;

__device__ inline unsigned short f2b(float f) {
    union { float f; unsigned int u; } a; a.f = f;
    unsigned int u = a.u;
    return (unsigned short)((u + 0x7FFF + ((u >> 16) & 1)) >> 16);  // RNE
}
__device__ inline float b2f(unsigned short b) {
    union { unsigned int u; float f; } a; a.u = ((unsigned int)b) << 16;
    return a.f;
}

// ---------------- init: h = x (fp32) and hb = bf16(x) ----------------
__global__ void k_init(const float* __restrict__ x, float* __restrict__ h,
                       ushort* __restrict__ hb) {
    int i = blockIdx.x * 256 + threadIdx.x;  // float4 index
    float4 v = ((const float4*)x)[i];
    ((float4*)h)[i] = v;
    ushort4 o;
    o.x = f2b(v.x); o.y = f2b(v.y); o.z = f2b(v.z); o.w = f2b(v.w);
    ((ushort4*)hb)[i] = o;
}

// ---------------- CSR build (bucketed, no global per-node histogram) --------
__global__ void k_bcur0(int* __restrict__ bcur) {
    int t = threadIdx.x;
    if (t < NBUCK) bcur[t] = t * BUCKCAP;
}

// Phase 1: scatter (src<<9 | dst&511) into padded per-bucket windows.
__global__ __launch_bounds__(256) void k_fill1(
    const int* __restrict__ srcv, const int* __restrict__ dstv,
    int* __restrict__ bcur, unsigned int* __restrict__ packed) {
    __shared__ int hist[NBUCK];
    __shared__ int base[NBUCK];
    int tid = threadIdx.x;
    int e0 = blockIdx.x * 4096;
    for (int i = tid; i < NBUCK; i += 256) hist[i] = 0;
    __syncthreads();
#pragma unroll
    for (int i = 0; i < 16; i++) {
        int e = e0 + i * 256 + tid;
        if (e < NEDGES) atomicAdd(&hist[dstv[e] >> 9], 1);
    }
    __syncthreads();
    for (int i = tid; i < NBUCK; i += 256) {
        int c = hist[i];
        base[i] = c ? atomicAdd(&bcur[i], c) : 0;
        hist[i] = 0;
    }
    __syncthreads();
#pragma unroll
    for (int i = 0; i < 16; i++) {
        int e = e0 + i * 256 + tid;
        if (e < NEDGES) {
            int d = dstv[e];
            int b = d >> 9;
            int r = atomicAdd(&hist[b], 1);
            packed[base[b] + r] = ((unsigned int)srcv[e] << 9) | (unsigned int)(d & 511);
        }
    }
}

// Phase 2: per bucket: LDS deg-hist -> LDS scan -> off2 (start,end) -> adj.
__global__ __launch_bounds__(256) void k_fill2(
    const unsigned int* __restrict__ packed, const int* __restrict__ bcur,
    int2* __restrict__ off2, int* __restrict__ adj) {
    __shared__ int deg[512];
    __shared__ int cur[512];
    int tid = threadIdx.x;
    int b = blockIdx.x;
    int base = b * BUCKCAP;
    int cnt = bcur[b] - base;
    deg[tid] = 0; deg[tid + 256] = 0;
    __syncthreads();
    for (int i = tid; i < cnt; i += 256)
        atomicAdd(&deg[packed[base + i] & 511], 1);
    __syncthreads();
    cur[tid] = deg[tid]; cur[tid + 256] = deg[tid + 256];
    __syncthreads();
    for (int o = 1; o < 512; o <<= 1) {
        int u0 = (tid >= o) ? cur[tid - o] : 0;
        int u1 = (tid + 256 >= o) ? cur[tid + 256 - o] : 0;
        __syncthreads();
        cur[tid] += u0; cur[tid + 256] += u1;
        __syncthreads();
    }
    int nbase = b * 512;
#pragma unroll
    for (int i = 0; i < 2; i++) {
        int t = tid + i * 256;
        int st = base + cur[t] - deg[t];   // exclusive scan + bucket base
        int n = nbase + t;
        if (n < NNODES) off2[n] = make_int2(st, st + deg[t]);
    }
    __syncthreads();
#pragma unroll
    for (int i = 0; i < 2; i++) {
        int t = tid + i * 256;
        cur[t] = base + cur[t] - deg[t];   // absolute cursors
    }
    __syncthreads();
    for (int i = tid; i < cnt; i += 256) {
        unsigned int p = packed[base + i];
        int r = atomicAdd(&cur[p & 511], 1);
        adj[r] = (int)(p >> 9);
    }
}

// ---------------- W transpose to bf16 (all 10 matrices, once) ----------------
__global__ void k_wt(const float* __restrict__ w1, const float* __restrict__ w2,
                     unsigned short* __restrict__ WT) {
    int t = blockIdx.x * 256 + threadIdx.x;
    int mat = t >> 14;
    int rem = t & 16383;
    int k = rem >> 7, n = rem & 127;
    const float* src = (mat < 5) ? &w1[(size_t)mat * 16384] : &w2[(size_t)(mat - 5) * 16384];
    WT[(size_t)mat * 16384 + n * 128 + k] = f2b(src[k * 128 + n]);
}

// ---------------- aggregation: zb = bf16(hb_self + sum_nbr hb) ----------------
__global__ void k_agg(const ushort* __restrict__ hb, const int2* __restrict__ off2,
                      const int* __restrict__ adj, ushort* __restrict__ zb) {
    int tid = threadIdx.x;
    int node = blockIdx.x * 8 + (tid >> 5);
    int d4 = tid & 31;
    const ushort4* hb4 = (const ushort4*)hb;
    ushort4 sv = hb4[(size_t)node * 32 + d4];
    float4 v = make_float4(b2f(sv.x), b2f(sv.y), b2f(sv.z), b2f(sv.w));
    int2 oo = off2[node];
    int e = oo.x, e1 = oo.y;
    for (; e + 8 <= e1; e += 8) {
        int s[8]; ushort4 u[8];
#pragma unroll
        for (int j = 0; j < 8; j++) s[j] = adj[e + j];
#pragma unroll
        for (int j = 0; j < 8; j++) u[j] = hb4[(size_t)s[j] * 32 + d4];
#pragma unroll
        for (int j = 0; j < 8; j++) {
            v.x += b2f(u[j].x); v.y += b2f(u[j].y);
            v.z += b2f(u[j].z); v.w += b2f(u[j].w);
        }
    }
    for (; e + 4 <= e1; e += 4) {
        int s0 = adj[e], s1 = adj[e + 1], s2 = adj[e + 2], s3 = adj[e + 3];
        ushort4 u0 = hb4[(size_t)s0 * 32 + d4];
        ushort4 u1 = hb4[(size_t)s1 * 32 + d4];
        ushort4 u2 = hb4[(size_t)s2 * 32 + d4];
        ushort4 u3 = hb4[(size_t)s3 * 32 + d4];
        v.x += (b2f(u0.x) + b2f(u1.x)) + (b2f(u2.x) + b2f(u3.x));
        v.y += (b2f(u0.y) + b2f(u1.y)) + (b2f(u2.y) + b2f(u3.y));
        v.z += (b2f(u0.z) + b2f(u1.z)) + (b2f(u2.z) + b2f(u3.z));
        v.w += (b2f(u0.w) + b2f(u1.w)) + (b2f(u2.w) + b2f(u3.w));
    }
    for (; e < e1; e++) {
        int s = adj[e];
        ushort4 u = hb4[(size_t)s * 32 + d4];
        v.x += b2f(u.x); v.y += b2f(u.y); v.z += b2f(u.z); v.w += b2f(u.w);
    }
    ushort4 o;
    o.x = f2b(v.x); o.y = f2b(v.y); o.z = f2b(v.z); o.w = f2b(v.w);
    ((ushort4*)zb)[(size_t)node * 32 + d4] = o;
}

// ---------------- GEMM1: tb = bf16(zb @ W + bias), stats -> replica ---------
__global__ __launch_bounds__(256) void k_gemm1(
    const ushort* __restrict__ A, const unsigned short* __restrict__ WT,
    const float* __restrict__ bias, ushort* __restrict__ C,
    float* __restrict__ stats) {
    __shared__ float lstat[256];
    int tid = threadIdx.x;
    int wave = tid >> 6;
    int lane = tid & 63;
    int q = lane >> 4;
    int l16 = lane & 15;
    int rowbase = blockIdx.x * 128 + wave * 32;

    f32x4 acc[2][8];
#pragma unroll
    for (int rt = 0; rt < 2; rt++)
#pragma unroll
        for (int nt = 0; nt < 8; nt++) acc[rt][nt] = (f32x4){0.f, 0.f, 0.f, 0.f};

    for (int kc = 0; kc < 4; kc++) {
        int k0 = kc * 32 + q * 8;
        short8 bf[8];
#pragma unroll
        for (int nt = 0; nt < 8; nt++)
            bf[nt] = *(const short8*)&WT[(size_t)(nt * 16 + l16) * 128 + k0];
#pragma unroll
        for (int rt = 0; rt < 2; rt++) {
            int row = rowbase + rt * 16 + l16;
            if (row >= NNODES) row = NNODES - 1;
            short8 av = *(const short8*)&A[(size_t)row * 128 + k0];
#pragma unroll
            for (int nt = 0; nt < 8; nt++)
                acc[rt][nt] = __builtin_amdgcn_mfma_f32_16x16x32_bf16(
                    av, bf[nt], acc[rt][nt], 0, 0, 0);
        }
    }

    lstat[tid] = 0.f;
    __syncthreads();
#pragma unroll
    for (int nt = 0; nt < 8; nt++) {
        float b = bias[nt * 16 + l16];
        float csum = 0.f, csq = 0.f;
#pragma unroll
        for (int rt = 0; rt < 2; rt++) {
            int rb = rowbase + rt * 16 + q * 4;
#pragma unroll
            for (int r = 0; r < 4; r++) {
                int row = rb + r;
                if (row < NNODES) {
                    float v = acc[rt][nt][r] + b;
                    C[(size_t)row * 128 + nt * 16 + l16] = f2b(v);
                    csum += v; csq += v * v;
                }
            }
        }
        csum += __shfl_xor(csum, 16, 64); csq += __shfl_xor(csq, 16, 64);
        csum += __shfl_xor(csum, 32, 64); csq += __shfl_xor(csq, 32, 64);
        if (q == 0) {
            atomicAdd(&lstat[nt * 16 + l16], csum);
            atomicAdd(&lstat[128 + nt * 16 + l16], csq);
        }
    }
    __syncthreads();
    atomicAdd(&stats[((blockIdx.x & (NREP - 1)) << 8) + tid], lstat[tid]);
}

// --------- GEMM2: t2b = bf16(relu(BN1(tb)) @ W + bias), stats -> replica ----
__global__ __launch_bounds__(256) void k_gemm2(
    const ushort* __restrict__ A, const unsigned short* __restrict__ WT,
    const float* __restrict__ bias, ushort* __restrict__ C,
    const float* __restrict__ statsIn, const float* __restrict__ gamma,
    const float* __restrict__ beta, float* __restrict__ stats) {
    __shared__ float lstat[256];
    __shared__ float s_sc[128], s_sh[128];
    int tid = threadIdx.x;
    if (tid < 128) {
        float s = 0.f, qq = 0.f;
#pragma unroll
        for (int r = 0; r < NREP; r++) {
            s  += statsIn[r * 256 + tid];
            qq += statsIn[r * 256 + 128 + tid];
        }
        float m = s * (1.f / NNODES);
        float var = qq * (1.f / NNODES) - m * m;
        float sc = gamma[tid] * rsqrtf(var + BN_EPS);
        s_sc[tid] = sc;
        s_sh[tid] = beta[tid] - m * sc;
    }
    __syncthreads();

    int wave = tid >> 6;
    int lane = tid & 63;
    int q = lane >> 4;
    int l16 = lane & 15;
    int rowbase = blockIdx.x * 128 + wave * 32;

    f32x4 acc[2][8];
#pragma unroll
    for (int rt = 0; rt < 2; rt++)
#pragma unroll
        for (int nt = 0; nt < 8; nt++) acc[rt][nt] = (f32x4){0.f, 0.f, 0.f, 0.f};

    for (int kc = 0; kc < 4; kc++) {
        int k0 = kc * 32 + q * 8;
        short8 bf[8];
#pragma unroll
        for (int nt = 0; nt < 8; nt++)
            bf[nt] = *(const short8*)&WT[(size_t)(nt * 16 + l16) * 128 + k0];

        float4 s0 = *(const float4*)&s_sc[k0];
        float4 s1 = *(const float4*)&s_sc[k0 + 4];
        float4 t0 = *(const float4*)&s_sh[k0];
        float4 t1 = *(const float4*)&s_sh[k0 + 4];
        float scl[8] = {s0.x, s0.y, s0.z, s0.w, s1.x, s1.y, s1.z, s1.w};
        float shf[8] = {t0.x, t0.y, t0.z, t0.w, t1.x, t1.y, t1.z, t1.w};
#pragma unroll
        for (int rt = 0; rt < 2; rt++) {
            int row = rowbase + rt * 16 + l16;
            if (row >= NNODES) row = NNODES - 1;
            union { short8 s; unsigned short u[8]; } in, cv;
            in.s = *(const short8*)&A[(size_t)row * 128 + k0];
#pragma unroll
            for (int j = 0; j < 8; j++) {
                float f = fmaxf(b2f(in.u[j]) * scl[j] + shf[j], 0.f);
                cv.u[j] = f2b(f);
            }
#pragma unroll
            for (int nt = 0; nt < 8; nt++)
                acc[rt][nt] = __builtin_amdgcn_mfma_f32_16x16x32_bf16(
                    cv.s, bf[nt], acc[rt][nt], 0, 0, 0);
        }
    }

    lstat[tid] = 0.f;
    __syncthreads();
#pragma unroll
    for (int nt = 0; nt < 8; nt++) {
        float b = bias[nt * 16 + l16];
        float csum = 0.f, csq = 0.f;
#pragma unroll
        for (int rt = 0; rt < 2; rt++) {
            int rb = rowbase + rt * 16 + q * 4;
#pragma unroll
            for (int r = 0; r < 4; r++) {
                int row = rb + r;
                if (row < NNODES) {
                    float v = acc[rt][nt][r] + b;
                    C[(size_t)row * 128 + nt * 16 + l16] = f2b(v);
                    csum += v; csq += v * v;
                }
            }
        }
        csum += __shfl_xor(csum, 16, 64); csq += __shfl_xor(csq, 16, 64);
        csum += __shfl_xor(csum, 32, 64); csq += __shfl_xor(csq, 32, 64);
        if (q == 0) {
            atomicAdd(&lstat[nt * 16 + l16], csum);
            atomicAdd(&lstat[128 + nt * 16 + l16], csq);
        }
    }
    __syncthreads();
    atomicAdd(&stats[((blockIdx.x & (NREP - 1)) << 8) + tid], lstat[tid]);
}

// ---- resid: h += relu(BN2(t2b)); hb = bf16(h). BN2 from replicated stats ---
__global__ void k_resid(float* __restrict__ h, ushort* __restrict__ hb,
                        const ushort* __restrict__ t2b,
                        const float* __restrict__ statsIn,
                        const float* __restrict__ gamma, const float* __restrict__ beta) {
    __shared__ float s_sc[128], s_sh[128];
    int tid = threadIdx.x;
    if (tid < 128) {
        float s = 0.f, qq = 0.f;
#pragma unroll
        for (int r = 0; r < NREP; r++) {
            s  += statsIn[r * 256 + tid];
            qq += statsIn[r * 256 + 128 + tid];
        }
        float m = s * (1.f / NNODES);
        float var = qq * (1.f / NNODES) - m * m;
        float sc = gamma[tid] * rsqrtf(var + BN_EPS);
        s_sc[tid] = sc;
        s_sh[tid] = beta[tid] - m * sc;
    }
    __syncthreads();
    int i = blockIdx.x * 256 + tid;
    int c4 = (i & 31) * 4;
    float4 sc = *(const float4*)&s_sc[c4];
    float4 sh = *(const float4*)&s_sh[c4];
    ushort4 t = ((const ushort4*)t2b)[i];
    float4 hv = ((float4*)h)[i];
    hv.x += fmaxf(b2f(t.x) * sc.x + sh.x, 0.f);
    hv.y += fmaxf(b2f(t.y) * sc.y + sh.y, 0.f);
    hv.z += fmaxf(b2f(t.z) * sc.z + sh.z, 0.f);
    hv.w += fmaxf(b2f(t.w) * sc.w + sh.w, 0.f);
    ((float4*)h)[i] = hv;
    ushort4 o;
    o.x = f2b(hv.x); o.y = f2b(hv.y); o.z = f2b(hv.z); o.w = f2b(hv.w);
    ((ushort4*)hb)[i] = o;
}

// ---------------- pooling + projection ----------------
__global__ void k_counts(const int* __restrict__ batch, float* __restrict__ cnt) {
    int g = threadIdx.x;
    if (g >= NGRAPHS) return;
    auto lb = [&](int key) {
        int lo = 0, hi = NNODES;
        while (lo < hi) {
            int mid = (lo + hi) >> 1;
            if (batch[mid] < key) lo = mid + 1; else hi = mid;
        }
        return lo;
    };
    cnt[g] = (float)(lb(g + 1) - lb(g));
}

__global__ void k_pool(const float* __restrict__ h, const int* __restrict__ batch,
                       float* __restrict__ pooled) {
    __shared__ float4 red[256];
    int t = threadIdx.x;
    int d4 = t & 31, sub = t >> 5;
    int n0 = blockIdx.x * 128;
    if (n0 >= NNODES) return;
    int n1 = n0 + 128; if (n1 > NNODES) n1 = NNODES;
    int glo = batch[n0], ghi = batch[n1 - 1];
    for (int g = glo; g <= ghi; g++) {
        float4 acc = make_float4(0.f, 0.f, 0.f, 0.f);
        for (int r = n0 + sub; r < n1; r += 8) {
            if (batch[r] == g) {
                float4 v = ((const float4*)h)[(size_t)r * 32 + d4];
                acc.x += v.x; acc.y += v.y; acc.z += v.z; acc.w += v.w;
            }
        }
        red[t] = acc;
        __syncthreads();
        if (sub < 4) {
            float4 o = red[t + 128];
            red[t].x += o.x; red[t].y += o.y; red[t].z += o.z; red[t].w += o.w;
        }
        __syncthreads();
        if (sub < 2) {
            float4 o = red[t + 64];
            red[t].x += o.x; red[t].y += o.y; red[t].z += o.z; red[t].w += o.w;
        }
        __syncthreads();
        if (sub == 0) {
            float4 o = red[t + 32];
            float4 a = red[t];
            a.x += o.x; a.y += o.y; a.z += o.z; a.w += o.w;
            atomicAdd(&pooled[g * 128 + d4 * 4 + 0], a.x);
            atomicAdd(&pooled[g * 128 + d4 * 4 + 1], a.y);
            atomicAdd(&pooled[g * 128 + d4 * 4 + 2], a.z);
            atomicAdd(&pooled[g * 128 + d4 * 4 + 3], a.w);
        }
        __syncthreads();
    }
}

__global__ void k_proj(const float* __restrict__ pooled, const float* __restrict__ cnt,
                       const float* __restrict__ wp, const float* __restrict__ bp,
                       float* __restrict__ out) {
    __shared__ float prow[128];
    int g = blockIdx.x, c = threadIdx.x;
    if (c < 128) prow[c] = pooled[g * 128 + c] / fmaxf(cnt[g], 1.f);
    __syncthreads();
    float acc = bp[c];
    for (int k = 0; k < 128; k++) acc += prow[k] * wp[k * 256 + c];
    out[g * 256 + c] = acc;
}

extern "C" void kernel_launch(void* const* d_in, const int* in_sizes, int n_in,
                              void* d_out, int out_size, void* d_ws, size_t ws_size,
                              hipStream_t stream) {
    const float* x    = (const float*)d_in[0];
    const int*   eidx = (const int*)d_in[1];
    const int*   batch= (const int*)d_in[2];
    const float* w1   = (const float*)d_in[3];
    const float* b1   = (const float*)d_in[4];
    const float* g1   = (const float*)d_in[5];
    const float* be1  = (const float*)d_in[6];
    const float* w2   = (const float*)d_in[7];
    const float* b2   = (const float*)d_in[8];
    const float* gbn  = (const float*)d_in[9];
    const float* bbn  = (const float*)d_in[10];
    const float* wp   = (const float*)d_in[11];
    const float* bp   = (const float*)d_in[12];

    float* out  = (float*)d_out;
    float* gemb = out;                          // [64,256]
    float* h    = out + (size_t)NGRAPHS * OUTD; // node_emb lives in d_out

    char* w = (char*)d_ws;
    ushort* hb   = (ushort*)w; w += (size_t)NNODES * 128 * 2; // bf16 mirror of h
    ushort* zb   = (ushort*)w; w += (size_t)NNODES * 128 * 2; // bf16 z
    ushort* tb   = (ushort*)w; w += (size_t)NNODES * 128 * 2; // bf16 t
    ushort* t2b  = (ushort*)w; w += (size_t)NNODES * 128 * 2; // bf16 t2
    int2*  off2  = (int2*)w;  w += (size_t)NNODES * 8;
    int*   adj   = (int*)w;   w += (size_t)NBUCK * BUCKCAP * 4;
    unsigned short* WT = (unsigned short*)w; w += (size_t)10 * 16384 * 2;
    int*   bcur  = (int*)w;   w += 256 * 4;
    float* statsAll = (float*)w; w += (size_t)10 * NREP * 256 * 4;
    float* pooled= (float*)w; w += (size_t)NGRAPHS * HID * 4;
    float* gcnt  = (float*)w; w += NGRAPHS * 4;

    // packed edge buffer aliases tb (dead until layer loop)
    unsigned int* packed = (unsigned int*)tb;

    const int* srcv = eidx;
    const int* dstv = eidx + NEDGES;

    // h = x, hb = bf16(x)
    k_init<<<NNODES * 32 / 256, 256, 0, stream>>>(x, h, hb);

    // W transposes (bf16), once
    k_wt<<<640, 256, 0, stream>>>(w1, w2, WT);

    // zero stats replicas + pooled + gcnt in one shot (contiguous)
    hipMemsetAsync(statsAll, 0,
                   ((size_t)10 * NREP * 256 + NGRAPHS * HID + NGRAPHS) * 4, stream);

    // CSR build: bucket scatter -> bucket-local hist/scan/fill
    k_bcur0<<<1, 256, 0, stream>>>(bcur);
    k_fill1<<<FILL_BLOCKS, 256, 0, stream>>>(srcv, dstv, bcur, packed);
    k_fill2<<<NBUCK, 256, 0, stream>>>(packed, bcur, off2, adj);

    const int GB = (NNODES + 127) / 128;  // 782
    for (int i = 0; i < NLAYERS; i++) {
        float* st1 = statsAll + (size_t)(2 * i) * NREP * 256;
        float* st2 = statsAll + (size_t)(2 * i + 1) * NREP * 256;
        k_agg<<<NNODES / 8, 256, 0, stream>>>(hb, off2, adj, zb);
        k_gemm1<<<GB, 256, 0, stream>>>(
            zb, WT + (size_t)i * 16384, b1 + i * HID, tb, st1);
        k_gemm2<<<GB, 256, 0, stream>>>(
            tb, WT + (size_t)(5 + i) * 16384, b2 + i * HID, t2b,
            st1, g1 + i * HID, be1 + i * HID, st2);
        k_resid<<<NNODES * 128 / 4 / 256, 256, 0, stream>>>(
            h, hb, t2b, st2, gbn + i * HID, bbn + i * HID);
    }

    // pooling + projection
    k_counts<<<1, 64, 0, stream>>>(batch, gcnt);
    k_pool<<<(NNODES + 127) / 128, 256, 0, stream>>>(h, batch, pooled);
    k_proj<<<NGRAPHS, 256, 0, stream>>>(pooled, gcnt, wp, bp, gemb);
}